// Round 1
// baseline (3408.980 us; speedup 1.0000x reference)
//
#include <hip/hip_runtime.h>
#include <cmath>

#define N_NODES 16384
#define DIM 128
#define EDIM 32
#define NEDGE 262144
#define NG 32
#define SEQ 512
#define NH 4
#define HD 32
#define TE 16

__device__ __forceinline__ float geluf(float x) {
    return 0.5f * x * (1.0f + erff(x * 0.70710678118654752f));
}

__device__ __forceinline__ float waveSum(float v) {
#pragma unroll
    for (int m = 1; m < 64; m <<= 1) v += __shfl_xor(v, m, 64);
    return v;
}

__device__ __forceinline__ float waveMax(float v) {
#pragma unroll
    for (int m = 1; m < 64; m <<= 1) v = fmaxf(v, __shfl_xor(v, m, 64));
    return v;
}

// --- LN over 128 features, 1 wave per row, 4 rows per block ---
__global__ __launch_bounds__(256) void ln_rows(const float* __restrict__ x,
                                               const float* __restrict__ g,
                                               const float* __restrict__ b,
                                               float* __restrict__ out) {
    int wave = threadIdx.x >> 6;
    int lane = threadIdx.x & 63;
    int row = blockIdx.x * 4 + wave;
    const float* xr = x + (size_t)row * DIM;
    float v0 = xr[lane], v1 = xr[lane + 64];
    float mean = waveSum(v0 + v1) * (1.0f / 128.0f);
    float d0 = v0 - mean, d1 = v1 - mean;
    float var = waveSum(d0 * d0 + d1 * d1) * (1.0f / 128.0f);
    float r = rsqrtf(var + 1e-5f);
    float* orow = out + (size_t)row * DIM;
    orow[lane] = d0 * r * g[lane] + b[lane];
    orow[lane + 64] = d1 * r * g[lane + 64] + b[lane + 64];
}

// --- edge MLP: msg = gelu([xn[dst], xn[src], attr] @ W1 + b1) @ W2 + b2; atomic scatter to aggr[dst]
__global__ __launch_bounds__(256) void edge_mlp(const float* __restrict__ xn,
                                                const int* __restrict__ ei,
                                                const float* __restrict__ attr,
                                                const float* __restrict__ w1,
                                                const float* __restrict__ b1,
                                                const float* __restrict__ w2,
                                                const float* __restrict__ b2,
                                                float* __restrict__ aggr) {
    __shared__ __align__(16) float in_s[288 * TE];   // [k][e]
    __shared__ __align__(16) float h_s[256 * TE];    // [k][e]
    __shared__ int ds[TE], ss[TE];
    int t = threadIdx.x;
    int eb = blockIdx.x * TE;
    if (t < TE) {
        ss[t] = ei[eb + t];           // source (x_j)
        ds[t] = ei[NEDGE + eb + t];   // target (x_i)
    }
    __syncthreads();
    // stage msg_in transposed: k-major, e contiguous
    for (int idx = t; idx < 288 * TE; idx += 256) {
        int e = idx / 288;
        int k = idx - e * 288;
        float v;
        if (k < 128)       v = xn[ds[e] * DIM + k];
        else if (k < 256)  v = xn[ss[e] * DIM + (k - 128)];
        else               v = attr[(eb + e) * EDIM + (k - 256)];
        in_s[k * TE + e] = v;
    }
    __syncthreads();
    // layer 1: thread t owns hidden column t for all 16 edges
    float acc[TE];
    {
        float bias = b1[t];
#pragma unroll
        for (int e = 0; e < TE; ++e) acc[e] = bias;
    }
    for (int k = 0; k < 288; ++k) {
        float w = w1[k * 256 + t];
        float av[16];
        *(float4*)&av[0]  = *(const float4*)&in_s[k * TE + 0];
        *(float4*)&av[4]  = *(const float4*)&in_s[k * TE + 4];
        *(float4*)&av[8]  = *(const float4*)&in_s[k * TE + 8];
        *(float4*)&av[12] = *(const float4*)&in_s[k * TE + 12];
#pragma unroll
        for (int e = 0; e < 16; ++e) acc[e] = fmaf(av[e], w, acc[e]);
    }
#pragma unroll
    for (int e = 0; e < TE; ++e) h_s[t * TE + e] = geluf(acc[e]);
    __syncthreads();
    // layer 2: thread (c = t&127, eg = t>>7) computes output col c for 8 edges
    int c = t & 127;
    int eg = t >> 7;
    float acc2[8];
    {
        float bias2 = b2[c];
#pragma unroll
        for (int j = 0; j < 8; ++j) acc2[j] = bias2;
    }
    for (int k = 0; k < 256; ++k) {
        float w = w2[k * 128 + c];
        float bv[8];
        *(float4*)&bv[0] = *(const float4*)&h_s[k * TE + eg * 8];
        *(float4*)&bv[4] = *(const float4*)&h_s[k * TE + eg * 8 + 4];
#pragma unroll
        for (int j = 0; j < 8; ++j) acc2[j] = fmaf(bv[j], w, acc2[j]);
    }
#pragma unroll
    for (int j = 0; j < 8; ++j) {
        int e = eg * 8 + j;
        atomicAdd(&aggr[ds[e] * DIM + c], acc2[j]);
    }
}

// --- node update MLP: h_local = gelu([xn, aggr] @ U1 + ub1) @ U2 + ub2
__global__ __launch_bounds__(128) void update_kernel(const float* __restrict__ xn,
                                                     const float* __restrict__ aggr,
                                                     const float* __restrict__ w1,
                                                     const float* __restrict__ b1,
                                                     const float* __restrict__ w2,
                                                     const float* __restrict__ b2,
                                                     float* __restrict__ h_local) {
    __shared__ float cat_s[256];
    __shared__ float u_s[128];
    int n = blockIdx.x, t = threadIdx.x;
    cat_s[t] = xn[n * DIM + t];
    cat_s[128 + t] = aggr[n * DIM + t];
    __syncthreads();
    float a = b1[t];
    for (int k = 0; k < 256; ++k) a = fmaf(cat_s[k], w1[k * 128 + t], a);
    u_s[t] = geluf(a);
    __syncthreads();
    float a2 = b2[t];
    for (int k = 0; k < 128; ++k) a2 = fmaf(u_s[k], w2[k * 128 + t], a2);
    h_local[n * DIM + t] = a2;
}

// --- qkv = x @ in_w + in_b
__global__ __launch_bounds__(128) void qkv_kernel(const float* __restrict__ x,
                                                  const float* __restrict__ w,
                                                  const float* __restrict__ b,
                                                  float* __restrict__ qkv) {
    __shared__ float xs[128];
    int n = blockIdx.x, t = threadIdx.x;
    xs[t] = x[n * DIM + t];
    __syncthreads();
    float a0 = b[t], a1 = b[t + 128], a2 = b[t + 256];
    for (int d = 0; d < 128; ++d) {
        float xv = xs[d];
        const float* wr = w + d * 384;
        a0 = fmaf(xv, wr[t], a0);
        a1 = fmaf(xv, wr[t + 128], a1);
        a2 = fmaf(xv, wr[t + 256], a2);
    }
    float* q = qkv + (size_t)n * 384;
    q[t] = a0; q[t + 128] = a1; q[t + 256] = a2;
}

// --- fused softmax attention: one block per (g, h, q-chunk of 128); wave per q-row group
__global__ __launch_bounds__(256) void attn_kernel(const float* __restrict__ qkv,
                                                   float* __restrict__ o) {
    int bid = blockIdx.x;
    int chunk = bid & 3;
    int h = (bid >> 2) & 3;
    int g = bid >> 4;
    int wave = threadIdx.x >> 6, lane = threadIdx.x & 63;
    __shared__ float p_s[4][512];
    const float scale = 0.17677669529663687f; // 1/sqrt(32)
    for (int r = 0; r < 32; ++r) {
        int sq = chunk * 128 + wave * 32 + r;
        int nq = g * SEQ + sq;
        const float* qr = qkv + (size_t)nq * 384 + h * HD;
        float q[32];
#pragma unroll
        for (int d = 0; d < 32; ++d) q[d] = qr[d] * scale;
        float sc[8];
#pragma unroll
        for (int m = 0; m < 8; ++m) {
            int j = lane + 64 * m;
            const float* kr = qkv + (size_t)(g * SEQ + j) * 384 + 128 + h * HD;
            float s = 0.0f;
#pragma unroll
            for (int d = 0; d < 32; ++d) s = fmaf(q[d], kr[d], s);
            sc[m] = s;
        }
        float mx = sc[0];
#pragma unroll
        for (int m = 1; m < 8; ++m) mx = fmaxf(mx, sc[m]);
        mx = waveMax(mx);
        float sum = 0.0f;
#pragma unroll
        for (int m = 0; m < 8; ++m) { sc[m] = expf(sc[m] - mx); sum += sc[m]; }
        sum = waveSum(sum);
        float inv = 1.0f / sum;
#pragma unroll
        for (int m = 0; m < 8; ++m) p_s[wave][lane + 64 * m] = sc[m] * inv;
        __syncthreads();
        // PV: lanes 0..31 own d, lanes 32..63 handle the odd key of each pair
        int dl = lane & 31, jh = lane >> 5;
        float oa = 0.0f;
        for (int jj = 0; jj < 512; jj += 2) {
            int j = jj + jh;
            float p = p_s[wave][j];
            float v = qkv[(size_t)(g * SEQ + j) * 384 + 256 + h * HD + dl];
            oa = fmaf(p, v, oa);
        }
        oa += __shfl_xor(oa, 32, 64);
        if (lane < 32) o[(size_t)nq * DIM + h * HD + lane] = oa;
        __syncthreads();
    }
}

// --- h1 = LN1(x + h_local + o @ out_w + out_b)
__global__ __launch_bounds__(128) void proj_res_ln(const float* __restrict__ x,
                                                   const float* __restrict__ h_local,
                                                   const float* __restrict__ o,
                                                   const float* __restrict__ ow,
                                                   const float* __restrict__ ob,
                                                   const float* __restrict__ g1,
                                                   const float* __restrict__ bb1,
                                                   float* __restrict__ h1) {
    __shared__ float o_s[128];
    __shared__ float red[4];
    int n = blockIdx.x, t = threadIdx.x;
    o_s[t] = o[n * DIM + t];
    __syncthreads();
    float a = ob[t];
    for (int d = 0; d < 128; ++d) a = fmaf(o_s[d], ow[d * 128 + t], a);
    float y = x[n * DIM + t] + h_local[n * DIM + t] + a;
    int wave = t >> 6, lane = t & 63;
    float s = waveSum(y);
    if (lane == 0) red[wave] = s;
    __syncthreads();
    float mean = (red[0] + red[1]) * (1.0f / 128.0f);
    float dv = y - mean;
    float s2 = waveSum(dv * dv);
    if (lane == 0) red[2 + wave] = s2;
    __syncthreads();
    float var = (red[2] + red[3]) * (1.0f / 128.0f);
    float r = rsqrtf(var + 1e-5f);
    h1[n * DIM + t] = dv * r * g1[t] + bb1[t];
}

// --- out = LN2(h1 + gelu(h1 @ F1 + fb1) @ F2 + fb2)
__global__ __launch_bounds__(256) void ffn_ln(const float* __restrict__ h1,
                                              const float* __restrict__ fw1,
                                              const float* __restrict__ fb1,
                                              const float* __restrict__ fw2,
                                              const float* __restrict__ fb2,
                                              const float* __restrict__ g2,
                                              const float* __restrict__ b2n,
                                              float* __restrict__ out) {
    __shared__ float h_s[128];
    __shared__ float hid_s[256];
    __shared__ float red[8];
    int n = blockIdx.x, t = threadIdx.x;
    if (t < 128) h_s[t] = h1[n * DIM + t];
    __syncthreads();
    float a = fb1[t];
    for (int d = 0; d < 128; ++d) a = fmaf(h_s[d], fw1[d * 256 + t], a);
    hid_s[t] = geluf(a);
    __syncthreads();
    float y = 0.0f;
    if (t < 128) {
        float f = fb2[t];
        for (int k = 0; k < 256; ++k) f = fmaf(hid_s[k], fw2[k * 128 + t], f);
        y = h_s[t] + f;
    }
    int wave = t >> 6, lane = t & 63;
    float s = waveSum(y);
    if (lane == 0) red[wave] = s;
    __syncthreads();
    float mean = (red[0] + red[1] + red[2] + red[3]) * (1.0f / 128.0f);
    float dv = (t < 128) ? (y - mean) : 0.0f;
    float s2 = waveSum(dv * dv);
    if (lane == 0) red[4 + wave] = s2;
    __syncthreads();
    float var = (red[4] + red[5] + red[6] + red[7]) * (1.0f / 128.0f);
    if (t < 128) {
        float r = rsqrtf(var + 1e-5f);
        out[n * DIM + t] = dv * r * g2[t] + b2n[t];
    }
}

extern "C" void kernel_launch(void* const* d_in, const int* in_sizes, int n_in,
                              void* d_out, int out_size, void* d_ws, size_t ws_size,
                              hipStream_t stream) {
    const float* x      = (const float*)d_in[0];
    const int*   ei     = (const int*)d_in[1];
    const float* attr   = (const float*)d_in[2];
    const float* gnn_g  = (const float*)d_in[4];
    const float* gnn_b  = (const float*)d_in[5];
    const float* msg_w1 = (const float*)d_in[6];
    const float* msg_b1 = (const float*)d_in[7];
    const float* msg_w2 = (const float*)d_in[8];
    const float* msg_b2 = (const float*)d_in[9];
    const float* upd_w1 = (const float*)d_in[10];
    const float* upd_b1 = (const float*)d_in[11];
    const float* upd_w2 = (const float*)d_in[12];
    const float* upd_b2 = (const float*)d_in[13];
    const float* in_w   = (const float*)d_in[14];
    const float* in_b   = (const float*)d_in[15];
    const float* out_w  = (const float*)d_in[16];
    const float* out_b  = (const float*)d_in[17];
    const float* ffn_w1 = (const float*)d_in[18];
    const float* ffn_b1 = (const float*)d_in[19];
    const float* ffn_w2 = (const float*)d_in[20];
    const float* ffn_b2 = (const float*)d_in[21];
    const float* n1_g   = (const float*)d_in[22];
    const float* n1_b   = (const float*)d_in[23];
    const float* n2_g   = (const float*)d_in[24];
    const float* n2_b   = (const float*)d_in[25];
    float* out = (float*)d_out;
    float* ws = (float*)d_ws;

    float* xn      = ws;
    float* aggr    = ws + 2097152;
    float* h_local = ws + 4194304;
    float* qkv     = ws + 6291456;   // N*384 = 6291456 floats
    float* o       = ws + 12582912;
    float* h1      = ws + 14680064;

    hipMemsetAsync(aggr, 0, (size_t)N_NODES * DIM * sizeof(float), stream);
    ln_rows<<<N_NODES / 4, 256, 0, stream>>>(x, gnn_g, gnn_b, xn);
    edge_mlp<<<NEDGE / TE, 256, 0, stream>>>(xn, ei, attr, msg_w1, msg_b1, msg_w2, msg_b2, aggr);
    update_kernel<<<N_NODES, 128, 0, stream>>>(xn, aggr, upd_w1, upd_b1, upd_w2, upd_b2, h_local);
    qkv_kernel<<<N_NODES, 128, 0, stream>>>(x, in_w, in_b, qkv);
    attn_kernel<<<NG * NH * 4, 256, 0, stream>>>(qkv, o);
    proj_res_ln<<<N_NODES, 128, 0, stream>>>(x, h_local, o, out_w, out_b, n1_g, n1_b, h1);
    ffn_ln<<<N_NODES, 256, 0, stream>>>(h1, ffn_w1, ffn_b1, ffn_w2, ffn_b2, n2_g, n2_b, out);
}

// Round 3
// 1520.059 us; speedup vs baseline: 2.2427x; 2.2427x over previous
//
#include <hip/hip_runtime.h>
#include <cmath>

#define N_NODES 16384
#define DIM 128
#define EDIM 32
#define NEDGE 262144
#define NG 32
#define SEQ 512
#define NH 4
#define HD 32
#define TE 16
#define CH 32

__device__ __forceinline__ float geluf(float x) {
    return 0.5f * x * (1.0f + erff(x * 0.70710678118654752f));
}

__device__ __forceinline__ float waveSum(float v) {
#pragma unroll
    for (int m = 1; m < 64; m <<= 1) v += __shfl_xor(v, m, 64);
    return v;
}

// --- LN over 128 features, 1 wave per row, 4 rows per block ---
__global__ __launch_bounds__(256) void ln_rows(const float* __restrict__ x,
                                               const float* __restrict__ g,
                                               const float* __restrict__ b,
                                               float* __restrict__ out) {
    int wave = threadIdx.x >> 6;
    int lane = threadIdx.x & 63;
    int row = blockIdx.x * 4 + wave;
    const float* xr = x + (size_t)row * DIM;
    float v0 = xr[lane], v1 = xr[lane + 64];
    float mean = waveSum(v0 + v1) * (1.0f / 128.0f);
    float d0 = v0 - mean, d1 = v1 - mean;
    float var = waveSum(d0 * d0 + d1 * d1) * (1.0f / 128.0f);
    float r = rsqrtf(var + 1e-5f);
    float* orow = out + (size_t)row * DIM;
    orow[lane] = d0 * r * g[lane] + b[lane];
    orow[lane + 64] = d1 * r * g[lane + 64] + b[lane + 64];
}

// --- edge MLP: msg = gelu([xn[dst], xn[src], attr] @ W1 + b1) @ W2 + b2; atomic scatter to aggr[dst]
__global__ __launch_bounds__(256) void edge_mlp(const float* __restrict__ xn,
                                                const int* __restrict__ ei,
                                                const float* __restrict__ attr,
                                                const float* __restrict__ w1,
                                                const float* __restrict__ b1,
                                                const float* __restrict__ w2,
                                                const float* __restrict__ b2,
                                                float* __restrict__ aggr) {
    __shared__ __align__(16) float in_s[288 * TE];   // [k][e]
    __shared__ __align__(16) float h_s[256 * TE];    // [k][e]
    __shared__ int ds[TE], ss[TE];
    int t = threadIdx.x;
    int eb = blockIdx.x * TE;
    if (t < TE) {
        ss[t] = ei[eb + t];           // source (x_j)
        ds[t] = ei[NEDGE + eb + t];   // target (x_i)
    }
    __syncthreads();
    // stage msg_in transposed: k-major, e contiguous
    for (int idx = t; idx < 288 * TE; idx += 256) {
        int e = idx / 288;
        int k = idx - e * 288;
        float v;
        if (k < 128)       v = xn[ds[e] * DIM + k];
        else if (k < 256)  v = xn[ss[e] * DIM + (k - 128)];
        else               v = attr[(eb + e) * EDIM + (k - 256)];
        in_s[k * TE + e] = v;
    }
    __syncthreads();
    // layer 1: thread t owns hidden column t for all 16 edges
    float acc[TE];
    {
        float bias = b1[t];
#pragma unroll
        for (int e = 0; e < TE; ++e) acc[e] = bias;
    }
    for (int k = 0; k < 288; ++k) {
        float w = w1[k * 256 + t];
        float av[16];
        *(float4*)&av[0]  = *(const float4*)&in_s[k * TE + 0];
        *(float4*)&av[4]  = *(const float4*)&in_s[k * TE + 4];
        *(float4*)&av[8]  = *(const float4*)&in_s[k * TE + 8];
        *(float4*)&av[12] = *(const float4*)&in_s[k * TE + 12];
#pragma unroll
        for (int e = 0; e < 16; ++e) acc[e] = fmaf(av[e], w, acc[e]);
    }
#pragma unroll
    for (int e = 0; e < TE; ++e) h_s[t * TE + e] = geluf(acc[e]);
    __syncthreads();
    // layer 2: thread (c = t&127, eg = t>>7) computes output col c for 8 edges
    int c = t & 127;
    int eg = t >> 7;
    float acc2[8];
    {
        float bias2 = b2[c];
#pragma unroll
        for (int j = 0; j < 8; ++j) acc2[j] = bias2;
    }
    for (int k = 0; k < 256; ++k) {
        float w = w2[k * 128 + c];
        float bv[8];
        *(float4*)&bv[0] = *(const float4*)&h_s[k * TE + eg * 8];
        *(float4*)&bv[4] = *(const float4*)&h_s[k * TE + eg * 8 + 4];
#pragma unroll
        for (int j = 0; j < 8; ++j) acc2[j] = fmaf(bv[j], w, acc2[j]);
    }
#pragma unroll
    for (int j = 0; j < 8; ++j) {
        int e = eg * 8 + j;
        atomicAdd(&aggr[ds[e] * DIM + c], acc2[j]);
    }
}

// --- node update MLP: h_local = gelu([xn, aggr] @ U1 + ub1) @ U2 + ub2
__global__ __launch_bounds__(128) void update_kernel(const float* __restrict__ xn,
                                                     const float* __restrict__ aggr,
                                                     const float* __restrict__ w1,
                                                     const float* __restrict__ b1,
                                                     const float* __restrict__ w2,
                                                     const float* __restrict__ b2,
                                                     float* __restrict__ h_local) {
    __shared__ float cat_s[256];
    __shared__ float u_s[128];
    int n = blockIdx.x, t = threadIdx.x;
    cat_s[t] = xn[n * DIM + t];
    cat_s[128 + t] = aggr[n * DIM + t];
    __syncthreads();
    float a = b1[t];
    for (int k = 0; k < 256; ++k) a = fmaf(cat_s[k], w1[k * 128 + t], a);
    u_s[t] = geluf(a);
    __syncthreads();
    float a2 = b2[t];
    for (int k = 0; k < 128; ++k) a2 = fmaf(u_s[k], w2[k * 128 + t], a2);
    h_local[n * DIM + t] = a2;
}

// --- qkv = x @ in_w + in_b
__global__ __launch_bounds__(128) void qkv_kernel(const float* __restrict__ x,
                                                  const float* __restrict__ w,
                                                  const float* __restrict__ b,
                                                  float* __restrict__ qkv) {
    __shared__ float xs[128];
    int n = blockIdx.x, t = threadIdx.x;
    xs[t] = x[n * DIM + t];
    __syncthreads();
    float a0 = b[t], a1 = b[t + 128], a2 = b[t + 256];
    for (int d = 0; d < 128; ++d) {
        float xv = xs[d];
        const float* wr = w + d * 384;
        a0 = fmaf(xv, wr[t], a0);
        a1 = fmaf(xv, wr[t + 128], a1);
        a2 = fmaf(xv, wr[t + 256], a2);
    }
    float* q = qkv + (size_t)n * 384;
    q[t] = a0; q[t + 128] = a1; q[t + 256] = a2;
}

// --- flash attention: block = (g, h, q-quarter); 256 threads = 128 queries x 2 key-splits
__global__ __launch_bounds__(256) void attn_flash(const float* __restrict__ qkv,
                                                  float* __restrict__ o) {
    int bid = blockIdx.x;
    int quarter = bid & 3;
    int h = (bid >> 2) & 3;
    int g = bid >> 4;
    int t = threadIdx.x;
    int qi = t & 127;       // query within quarter
    int sp = t >> 7;        // key split 0/1
    int sq = quarter * 128 + qi;
    int nq = g * SEQ + sq;

    __shared__ __align__(16) float k_s[2][CH][HD];   // 8 KB
    __shared__ __align__(16) float v_s[2][CH][HD];   // 8 KB
    __shared__ float merge_s[128][34];               // 17.4 KB: m,l,o[32] of split 1

    float qv[HD];
    const float* qr = qkv + (size_t)nq * 384 + h * HD;
#pragma unroll
    for (int d = 0; d < HD; d += 4) *(float4*)&qv[d] = *(const float4*)&qr[d];
    const float scale = 0.17677669529663687f;  // 1/sqrt(32)
#pragma unroll
    for (int d = 0; d < HD; ++d) qv[d] *= scale;

    float m = -1e30f, l = 0.0f;
    float oacc[HD];
#pragma unroll
    for (int d = 0; d < HD; ++d) oacc[d] = 0.0f;

    int base_j = sp * 256;
    int r = qi >> 3;          // 0..15: row within staging pass
    int c4 = (qi & 7) * 4;    // float4 column
    for (int c0 = 0; c0 < 256; c0 += CH) {
        __syncthreads();
        // each 128-thread split group stages its own chunk of K and V
#pragma unroll
        for (int p = 0; p < CH; p += 16) {
            int j = base_j + c0 + p + r;
            const float* kr = qkv + (size_t)(g * SEQ + j) * 384 + 128 + h * HD;
            const float* vr = qkv + (size_t)(g * SEQ + j) * 384 + 256 + h * HD;
            *(float4*)&k_s[sp][p + r][c4] = *(const float4*)&kr[c4];
            *(float4*)&v_s[sp][p + r][c4] = *(const float4*)&vr[c4];
        }
        __syncthreads();
        float sc[CH];
#pragma unroll
        for (int j = 0; j < CH; ++j) {
            float s = 0.0f;
#pragma unroll
            for (int d = 0; d < HD; ++d) s = fmaf(qv[d], k_s[sp][j][d], s);
            sc[j] = s;
        }
        float cm = sc[0];
#pragma unroll
        for (int j = 1; j < CH; ++j) cm = fmaxf(cm, sc[j]);
        float mn = fmaxf(m, cm);
        float corr = __expf(m - mn);
        l *= corr;
#pragma unroll
        for (int d = 0; d < HD; ++d) oacc[d] *= corr;
#pragma unroll
        for (int j = 0; j < CH; ++j) {
            float p = __expf(sc[j] - mn);
            l += p;
#pragma unroll
            for (int d = 0; d < HD; ++d) oacc[d] = fmaf(p, v_s[sp][j][d], oacc[d]);
        }
        m = mn;
    }
    // merge split 1 into split 0 via LDS
    __syncthreads();
    if (sp == 1) {
        merge_s[qi][0] = m;
        merge_s[qi][1] = l;
#pragma unroll
        for (int d = 0; d < HD; ++d) merge_s[qi][2 + d] = oacc[d];
    }
    __syncthreads();
    if (sp == 0) {
        float m1 = merge_s[qi][0], l1 = merge_s[qi][1];
        float mn = fmaxf(m, m1);
        float cc0 = __expf(m - mn), cc1 = __expf(m1 - mn);
        float inv = 1.0f / (cc0 * l + cc1 * l1);
        float* orow = o + (size_t)nq * DIM + h * HD;
#pragma unroll
        for (int d = 0; d < HD; ++d)
            orow[d] = (cc0 * oacc[d] + cc1 * merge_s[qi][2 + d]) * inv;
    }
}

// --- h1 = LN1(x + h_local + o @ out_w + out_b)
__global__ __launch_bounds__(128) void proj_res_ln(const float* __restrict__ x,
                                                   const float* __restrict__ h_local,
                                                   const float* __restrict__ o,
                                                   const float* __restrict__ ow,
                                                   const float* __restrict__ ob,
                                                   const float* __restrict__ g1,
                                                   const float* __restrict__ bb1,
                                                   float* __restrict__ h1) {
    __shared__ float o_s[128];
    __shared__ float red[4];
    int n = blockIdx.x, t = threadIdx.x;
    o_s[t] = o[n * DIM + t];
    __syncthreads();
    float a = ob[t];
    for (int d = 0; d < 128; ++d) a = fmaf(o_s[d], ow[d * 128 + t], a);
    float y = x[n * DIM + t] + h_local[n * DIM + t] + a;
    int wave = t >> 6, lane = t & 63;
    float s = waveSum(y);
    if (lane == 0) red[wave] = s;
    __syncthreads();
    float mean = (red[0] + red[1]) * (1.0f / 128.0f);
    float dv = y - mean;
    float s2 = waveSum(dv * dv);
    if (lane == 0) red[2 + wave] = s2;
    __syncthreads();
    float var = (red[2] + red[3]) * (1.0f / 128.0f);
    float r = rsqrtf(var + 1e-5f);
    h1[n * DIM + t] = dv * r * g1[t] + bb1[t];
}

// --- out = LN2(h1 + gelu(h1 @ F1 + fb1) @ F2 + fb2)
__global__ __launch_bounds__(256) void ffn_ln(const float* __restrict__ h1,
                                              const float* __restrict__ fw1,
                                              const float* __restrict__ fb1,
                                              const float* __restrict__ fw2,
                                              const float* __restrict__ fb2,
                                              const float* __restrict__ g2,
                                              const float* __restrict__ b2n,
                                              float* __restrict__ out) {
    __shared__ float h_s[128];
    __shared__ float hid_s[256];
    __shared__ float red[8];
    int n = blockIdx.x, t = threadIdx.x;
    if (t < 128) h_s[t] = h1[n * DIM + t];
    __syncthreads();
    float a = fb1[t];
    for (int d = 0; d < 128; ++d) a = fmaf(h_s[d], fw1[d * 256 + t], a);
    hid_s[t] = geluf(a);
    __syncthreads();
    float y = 0.0f;
    if (t < 128) {
        float f = fb2[t];
        for (int k = 0; k < 256; ++k) f = fmaf(hid_s[k], fw2[k * 128 + t], f);
        y = h_s[t] + f;
    }
    int wave = t >> 6, lane = t & 63;
    float s = waveSum(y);
    if (lane == 0) red[wave] = s;
    __syncthreads();
    float mean = (red[0] + red[1] + red[2] + red[3]) * (1.0f / 128.0f);
    float dv = (t < 128) ? (y - mean) : 0.0f;
    float s2 = waveSum(dv * dv);
    if (lane == 0) red[4 + wave] = s2;
    __syncthreads();
    float var = (red[4] + red[5] + red[6] + red[7]) * (1.0f / 128.0f);
    if (t < 128) {
        float r = rsqrtf(var + 1e-5f);
        out[n * DIM + t] = dv * r * g2[t] + b2n[t];
    }
}

extern "C" void kernel_launch(void* const* d_in, const int* in_sizes, int n_in,
                              void* d_out, int out_size, void* d_ws, size_t ws_size,
                              hipStream_t stream) {
    const float* x      = (const float*)d_in[0];
    const int*   ei     = (const int*)d_in[1];
    const float* attr   = (const float*)d_in[2];
    const float* gnn_g  = (const float*)d_in[4];
    const float* gnn_b  = (const float*)d_in[5];
    const float* msg_w1 = (const float*)d_in[6];
    const float* msg_b1 = (const float*)d_in[7];
    const float* msg_w2 = (const float*)d_in[8];
    const float* msg_b2 = (const float*)d_in[9];
    const float* upd_w1 = (const float*)d_in[10];
    const float* upd_b1 = (const float*)d_in[11];
    const float* upd_w2 = (const float*)d_in[12];
    const float* upd_b2 = (const float*)d_in[13];
    const float* in_w   = (const float*)d_in[14];
    const float* in_b   = (const float*)d_in[15];
    const float* out_w  = (const float*)d_in[16];
    const float* out_b  = (const float*)d_in[17];
    const float* ffn_w1 = (const float*)d_in[18];
    const float* ffn_b1 = (const float*)d_in[19];
    const float* ffn_w2 = (const float*)d_in[20];
    const float* ffn_b2 = (const float*)d_in[21];
    const float* n1_g   = (const float*)d_in[22];
    const float* n1_b   = (const float*)d_in[23];
    const float* n2_g   = (const float*)d_in[24];
    const float* n2_b   = (const float*)d_in[25];
    float* out = (float*)d_out;
    float* ws = (float*)d_ws;

    float* xn      = ws;
    float* aggr    = ws + 2097152;
    float* h_local = ws + 4194304;
    float* qkv     = ws + 6291456;   // N*384 = 6291456 floats
    float* o       = ws + 12582912;
    float* h1      = ws + 14680064;

    hipMemsetAsync(aggr, 0, (size_t)N_NODES * DIM * sizeof(float), stream);
    ln_rows<<<N_NODES / 4, 256, 0, stream>>>(x, gnn_g, gnn_b, xn);
    edge_mlp<<<NEDGE / TE, 256, 0, stream>>>(xn, ei, attr, msg_w1, msg_b1, msg_w2, msg_b2, aggr);
    update_kernel<<<N_NODES, 128, 0, stream>>>(xn, aggr, upd_w1, upd_b1, upd_w2, upd_b2, h_local);
    qkv_kernel<<<N_NODES, 128, 0, stream>>>(x, in_w, in_b, qkv);
    attn_flash<<<NG * NH * 4, 256, 0, stream>>>(qkv, o);
    proj_res_ln<<<N_NODES, 128, 0, stream>>>(x, h_local, o, out_w, out_b, n1_g, n1_b, h1);
    ffn_ln<<<N_NODES, 256, 0, stream>>>(h1, ffn_w1, ffn_b1, ffn_w2, ffn_b2, n2_g, n2_b, out);
}

// Round 4
// 779.837 us; speedup vs baseline: 4.3714x; 1.9492x over previous
//
#include <hip/hip_runtime.h>
#include <cmath>

#define N_NODES 16384
#define DIM 128
#define EDIM 32
#define NEDGE 262144
#define NG 32
#define SEQ 512
#define NH 4
#define HD 32
#define CH 32

#define EB 64       // edges per block in edge MLP
#define K1 288
#define K1P 296     // padded LDS row (ushorts): 592B = 37*16, 20 words mod 32 -> 2-way
#define H1 256
#define H1P 264     // 528B = 33*16, 4 words mod 32 -> 2-way

typedef __bf16 bf16x8 __attribute__((ext_vector_type(8)));
typedef float f32x4 __attribute__((ext_vector_type(4)));

__device__ __forceinline__ unsigned short f2bf(float f) {
    union { float f; unsigned int u; } v; v.f = f;
    unsigned int r = (v.u + 0x7FFFu + ((v.u >> 16) & 1u)) >> 16;
    return (unsigned short)r;
}

__device__ __forceinline__ float geluf(float x) {
    return 0.5f * x * (1.0f + erff(x * 0.70710678118654752f));
}

__device__ __forceinline__ float waveSum(float v) {
#pragma unroll
    for (int m = 1; m < 64; m <<= 1) v += __shfl_xor(v, m, 64);
    return v;
}

// --- LN over 128 features; writes f32 and bf16 copies ---
__global__ __launch_bounds__(256) void ln_rows_bf(const float* __restrict__ x,
                                                  const float* __restrict__ g,
                                                  const float* __restrict__ b,
                                                  float* __restrict__ out,
                                                  unsigned short* __restrict__ out_bf) {
    int wave = threadIdx.x >> 6;
    int lane = threadIdx.x & 63;
    int row = blockIdx.x * 4 + wave;
    const float* xr = x + (size_t)row * DIM;
    float v0 = xr[lane], v1 = xr[lane + 64];
    float mean = waveSum(v0 + v1) * (1.0f / 128.0f);
    float d0 = v0 - mean, d1 = v1 - mean;
    float var = waveSum(d0 * d0 + d1 * d1) * (1.0f / 128.0f);
    float r = rsqrtf(var + 1e-5f);
    float y0 = d0 * r * g[lane] + b[lane];
    float y1 = d1 * r * g[lane + 64] + b[lane + 64];
    float* orow = out + (size_t)row * DIM;
    orow[lane] = y0;
    orow[lane + 64] = y1;
    unsigned short* obf = out_bf + (size_t)row * DIM;
    obf[lane] = f2bf(y0);
    obf[lane + 64] = f2bf(y1);
}

// --- attr f32 -> bf16, 8 elems/thread ---
__global__ __launch_bounds__(256) void conv_attr(const float* __restrict__ a,
                                                 unsigned short* __restrict__ abf) {
    size_t i = ((size_t)blockIdx.x * 256 + threadIdx.x) * 8;
    float4 x0 = *(const float4*)&a[i];
    float4 x1 = *(const float4*)&a[i + 4];
    unsigned short r[8];
    r[0] = f2bf(x0.x); r[1] = f2bf(x0.y); r[2] = f2bf(x0.z); r[3] = f2bf(x0.w);
    r[4] = f2bf(x1.x); r[5] = f2bf(x1.y); r[6] = f2bf(x1.z); r[7] = f2bf(x1.w);
    *(uint4*)&abf[i] = *(const uint4*)r;
}

// --- w1 [288][256] f32 -> w1t [256][288] bf16 ---
__global__ __launch_bounds__(256) void conv_w1t(const float* __restrict__ w,
                                                unsigned short* __restrict__ wt) {
    int idx = blockIdx.x * 256 + threadIdx.x;  // 288*256 = 73728
    int k = idx >> 8, n = idx & 255;
    wt[n * K1 + k] = f2bf(w[idx]);
}

// --- w2 [256][128] f32 -> w2t [128][256] bf16 ---
__global__ __launch_bounds__(256) void conv_w2t(const float* __restrict__ w,
                                                unsigned short* __restrict__ wt) {
    int idx = blockIdx.x * 256 + threadIdx.x;  // 256*128 = 32768
    int k = idx >> 7, n = idx & 127;
    wt[n * H1 + k] = f2bf(w[idx]);
}

// --- edge MLP with bf16 MFMA: 64 edges/block, 4 waves (wave = 64 hidden cols L1, 32 out cols L2)
__global__ __launch_bounds__(256, 2) void edge_mlp_mfma(const unsigned short* __restrict__ xn_bf,
                                                        const int* __restrict__ ei,
                                                        const unsigned short* __restrict__ attr_bf,
                                                        const unsigned short* __restrict__ w1t,
                                                        const float* __restrict__ b1,
                                                        const unsigned short* __restrict__ w2t,
                                                        const float* __restrict__ b2,
                                                        float* __restrict__ aggr) {
    __shared__ __align__(16) unsigned short in_s[EB][K1P];  // 37888 B
    __shared__ __align__(16) unsigned short h_s[EB][H1P];   // 33792 B
    __shared__ int ds[EB], ss[EB];
    int t = threadIdx.x;
    int eb0 = blockIdx.x * EB;
    if (t < EB) ds[t] = ei[NEDGE + eb0 + t];
    else if (t < 2 * EB) ss[t - EB] = ei[eb0 + t - EB];
    __syncthreads();
    // stage IN = [xn[dst] | xn[src] | attr] as bf16, 36 x 16B per edge
    for (int idx = t; idx < EB * 36; idx += 256) {
        int e = idx / 36;
        int seg = idx - e * 36;
        const unsigned short* src;
        if (seg < 16)      src = xn_bf + (size_t)ds[e] * DIM + seg * 8;
        else if (seg < 32) src = xn_bf + (size_t)ss[e] * DIM + (seg - 16) * 8;
        else               src = attr_bf + (size_t)(eb0 + e) * EDIM + (seg - 32) * 8;
        *(uint4*)&in_s[e][seg * 8] = *(const uint4*)src;
    }
    __syncthreads();

    int w = t >> 6;
    int lane = t & 63;
    int l15 = lane & 15;
    int kq = lane >> 4;   // 0..3

    // ---- layer 1: H[64][256] = IN[64][288] @ W1[288][256], wave w owns cols [w*64, w*64+64)
    f32x4 acc[4][4] = {};
    for (int kk = 0; kk < 9; ++kk) {
        bf16x8 a[4], bw[4];
#pragma unroll
        for (int mi = 0; mi < 4; ++mi)
            a[mi] = *(const bf16x8*)&in_s[mi * 16 + l15][kk * 32 + kq * 8];
#pragma unroll
        for (int ni = 0; ni < 4; ++ni)
            bw[ni] = *(const bf16x8*)&w1t[(size_t)((w << 6) + ni * 16 + l15) * K1 + kk * 32 + kq * 8];
#pragma unroll
        for (int mi = 0; mi < 4; ++mi)
#pragma unroll
            for (int ni = 0; ni < 4; ++ni)
                acc[mi][ni] = __builtin_amdgcn_mfma_f32_16x16x32_bf16(a[mi], bw[ni], acc[mi][ni], 0, 0, 0);
    }
    // bias + gelu -> h_s (C layout: col = lane&15, row = (lane>>4)*4 + reg)
#pragma unroll
    for (int mi = 0; mi < 4; ++mi)
#pragma unroll
        for (int ni = 0; ni < 4; ++ni) {
            int col = (w << 6) + ni * 16 + l15;
            float bias = b1[col];
#pragma unroll
            for (int j = 0; j < 4; ++j) {
                int row = mi * 16 + kq * 4 + j;
                h_s[row][col] = f2bf(geluf(acc[mi][ni][j] + bias));
            }
        }
    __syncthreads();

    // ---- layer 2: MSG[64][128] = H[64][256] @ W2[256][128], wave w owns cols [w*32, w*32+32)
    f32x4 acc2[4][2] = {};
    for (int kk = 0; kk < 8; ++kk) {
        bf16x8 a2[4], bw2[2];
#pragma unroll
        for (int mi = 0; mi < 4; ++mi)
            a2[mi] = *(const bf16x8*)&h_s[mi * 16 + l15][kk * 32 + kq * 8];
#pragma unroll
        for (int ni = 0; ni < 2; ++ni)
            bw2[ni] = *(const bf16x8*)&w2t[(size_t)((w << 5) + ni * 16 + l15) * H1 + kk * 32 + kq * 8];
#pragma unroll
        for (int mi = 0; mi < 4; ++mi)
#pragma unroll
            for (int ni = 0; ni < 2; ++ni)
                acc2[mi][ni] = __builtin_amdgcn_mfma_f32_16x16x32_bf16(a2[mi], bw2[ni], acc2[mi][ni], 0, 0, 0);
    }
    // bias + atomic scatter-add to aggr[dst]
#pragma unroll
    for (int mi = 0; mi < 4; ++mi)
#pragma unroll
        for (int ni = 0; ni < 2; ++ni) {
            int col = (w << 5) + ni * 16 + l15;
            float bias = b2[col];
#pragma unroll
            for (int j = 0; j < 4; ++j) {
                int row = mi * 16 + kq * 4 + j;
                atomicAdd(&aggr[(size_t)ds[row] * DIM + col], acc2[mi][ni][j] + bias);
            }
        }
}

// --- node update MLP: h_local = gelu([xn, aggr] @ U1 + ub1) @ U2 + ub2
__global__ __launch_bounds__(128) void update_kernel(const float* __restrict__ xn,
                                                     const float* __restrict__ aggr,
                                                     const float* __restrict__ w1,
                                                     const float* __restrict__ b1,
                                                     const float* __restrict__ w2,
                                                     const float* __restrict__ b2,
                                                     float* __restrict__ h_local) {
    __shared__ float cat_s[256];
    __shared__ float u_s[128];
    int n = blockIdx.x, t = threadIdx.x;
    cat_s[t] = xn[n * DIM + t];
    cat_s[128 + t] = aggr[n * DIM + t];
    __syncthreads();
    float a = b1[t];
    for (int k = 0; k < 256; ++k) a = fmaf(cat_s[k], w1[k * 128 + t], a);
    u_s[t] = geluf(a);
    __syncthreads();
    float a2 = b2[t];
    for (int k = 0; k < 128; ++k) a2 = fmaf(u_s[k], w2[k * 128 + t], a2);
    h_local[n * DIM + t] = a2;
}

// --- qkv = x @ in_w + in_b
__global__ __launch_bounds__(128) void qkv_kernel(const float* __restrict__ x,
                                                  const float* __restrict__ w,
                                                  const float* __restrict__ b,
                                                  float* __restrict__ qkv) {
    __shared__ float xs[128];
    int n = blockIdx.x, t = threadIdx.x;
    xs[t] = x[n * DIM + t];
    __syncthreads();
    float a0 = b[t], a1 = b[t + 128], a2 = b[t + 256];
    for (int d = 0; d < 128; ++d) {
        float xv = xs[d];
        const float* wr = w + d * 384;
        a0 = fmaf(xv, wr[t], a0);
        a1 = fmaf(xv, wr[t + 128], a1);
        a2 = fmaf(xv, wr[t + 256], a2);
    }
    float* q = qkv + (size_t)n * 384;
    q[t] = a0; q[t + 128] = a1; q[t + 256] = a2;
}

// --- flash attention: block = (g, h, q-quarter); 256 threads = 128 queries x 2 key-splits
__global__ __launch_bounds__(256) void attn_flash(const float* __restrict__ qkv,
                                                  float* __restrict__ o) {
    int bid = blockIdx.x;
    int quarter = bid & 3;
    int h = (bid >> 2) & 3;
    int g = bid >> 4;
    int t = threadIdx.x;
    int qi = t & 127;       // query within quarter
    int sp = t >> 7;        // key split 0/1
    int sq = quarter * 128 + qi;
    int nq = g * SEQ + sq;

    __shared__ __align__(16) float k_s[2][CH][HD];
    __shared__ __align__(16) float v_s[2][CH][HD];
    __shared__ float merge_s[128][34];

    float qv[HD];
    const float* qr = qkv + (size_t)nq * 384 + h * HD;
#pragma unroll
    for (int d = 0; d < HD; d += 4) *(float4*)&qv[d] = *(const float4*)&qr[d];
    const float scale = 0.17677669529663687f;
#pragma unroll
    for (int d = 0; d < HD; ++d) qv[d] *= scale;

    float m = -1e30f, l = 0.0f;
    float oacc[HD];
#pragma unroll
    for (int d = 0; d < HD; ++d) oacc[d] = 0.0f;

    int base_j = sp * 256;
    int r = qi >> 3;
    int c4 = (qi & 7) * 4;
    for (int c0 = 0; c0 < 256; c0 += CH) {
        __syncthreads();
#pragma unroll
        for (int p = 0; p < CH; p += 16) {
            int j = base_j + c0 + p + r;
            const float* kr = qkv + (size_t)(g * SEQ + j) * 384 + 128 + h * HD;
            const float* vr = qkv + (size_t)(g * SEQ + j) * 384 + 256 + h * HD;
            *(float4*)&k_s[sp][p + r][c4] = *(const float4*)&kr[c4];
            *(float4*)&v_s[sp][p + r][c4] = *(const float4*)&vr[c4];
        }
        __syncthreads();
        float sc[CH];
#pragma unroll
        for (int j = 0; j < CH; ++j) {
            float s = 0.0f;
#pragma unroll
            for (int d = 0; d < HD; ++d) s = fmaf(qv[d], k_s[sp][j][d], s);
            sc[j] = s;
        }
        float cm = sc[0];
#pragma unroll
        for (int j = 1; j < CH; ++j) cm = fmaxf(cm, sc[j]);
        float mn = fmaxf(m, cm);
        float corr = __expf(m - mn);
        l *= corr;
#pragma unroll
        for (int d = 0; d < HD; ++d) oacc[d] *= corr;
#pragma unroll
        for (int j = 0; j < CH; ++j) {
            float p = __expf(sc[j] - mn);
            l += p;
#pragma unroll
            for (int d = 0; d < HD; ++d) oacc[d] = fmaf(p, v_s[sp][j][d], oacc[d]);
        }
        m = mn;
    }
    __syncthreads();
    if (sp == 1) {
        merge_s[qi][0] = m;
        merge_s[qi][1] = l;
#pragma unroll
        for (int d = 0; d < HD; ++d) merge_s[qi][2 + d] = oacc[d];
    }
    __syncthreads();
    if (sp == 0) {
        float m1 = merge_s[qi][0], l1 = merge_s[qi][1];
        float mn = fmaxf(m, m1);
        float cc0 = __expf(m - mn), cc1 = __expf(m1 - mn);
        float inv = 1.0f / (cc0 * l + cc1 * l1);
        float* orow = o + (size_t)nq * DIM + h * HD;
#pragma unroll
        for (int d = 0; d < HD; ++d)
            orow[d] = (cc0 * oacc[d] + cc1 * merge_s[qi][2 + d]) * inv;
    }
}

// --- h1 = LN1(x + h_local + o @ out_w + out_b)
__global__ __launch_bounds__(128) void proj_res_ln(const float* __restrict__ x,
                                                   const float* __restrict__ h_local,
                                                   const float* __restrict__ o,
                                                   const float* __restrict__ ow,
                                                   const float* __restrict__ ob,
                                                   const float* __restrict__ g1,
                                                   const float* __restrict__ bb1,
                                                   float* __restrict__ h1) {
    __shared__ float o_s[128];
    __shared__ float red[4];
    int n = blockIdx.x, t = threadIdx.x;
    o_s[t] = o[n * DIM + t];
    __syncthreads();
    float a = ob[t];
    for (int d = 0; d < 128; ++d) a = fmaf(o_s[d], ow[d * 128 + t], a);
    float y = x[n * DIM + t] + h_local[n * DIM + t] + a;
    int wave = t >> 6, lane = t & 63;
    float s = waveSum(y);
    if (lane == 0) red[wave] = s;
    __syncthreads();
    float mean = (red[0] + red[1]) * (1.0f / 128.0f);
    float dv = y - mean;
    float s2 = waveSum(dv * dv);
    if (lane == 0) red[2 + wave] = s2;
    __syncthreads();
    float var = (red[2] + red[3]) * (1.0f / 128.0f);
    float r = rsqrtf(var + 1e-5f);
    h1[n * DIM + t] = dv * r * g1[t] + bb1[t];
}

// --- out = LN2(h1 + gelu(h1 @ F1 + fb1) @ F2 + fb2)
__global__ __launch_bounds__(256) void ffn_ln(const float* __restrict__ h1,
                                              const float* __restrict__ fw1,
                                              const float* __restrict__ fb1,
                                              const float* __restrict__ fw2,
                                              const float* __restrict__ fb2,
                                              const float* __restrict__ g2,
                                              const float* __restrict__ b2n,
                                              float* __restrict__ out) {
    __shared__ float h_s[128];
    __shared__ float hid_s[256];
    __shared__ float red[8];
    int n = blockIdx.x, t = threadIdx.x;
    if (t < 128) h_s[t] = h1[n * DIM + t];
    __syncthreads();
    float a = fb1[t];
    for (int d = 0; d < 128; ++d) a = fmaf(h_s[d], fw1[d * 256 + t], a);
    hid_s[t] = geluf(a);
    __syncthreads();
    float y = 0.0f;
    if (t < 128) {
        float f = fb2[t];
        for (int k = 0; k < 256; ++k) f = fmaf(hid_s[k], fw2[k * 128 + t], f);
        y = h_s[t] + f;
    }
    int wave = t >> 6, lane = t & 63;
    float s = waveSum(y);
    if (lane == 0) red[wave] = s;
    __syncthreads();
    float mean = (red[0] + red[1] + red[2] + red[3]) * (1.0f / 128.0f);
    float dv = (t < 128) ? (y - mean) : 0.0f;
    float s2 = waveSum(dv * dv);
    if (lane == 0) red[4 + wave] = s2;
    __syncthreads();
    float var = (red[4] + red[5] + red[6] + red[7]) * (1.0f / 128.0f);
    if (t < 128) {
        float r = rsqrtf(var + 1e-5f);
        out[n * DIM + t] = dv * r * g2[t] + b2n[t];
    }
}

extern "C" void kernel_launch(void* const* d_in, const int* in_sizes, int n_in,
                              void* d_out, int out_size, void* d_ws, size_t ws_size,
                              hipStream_t stream) {
    const float* x      = (const float*)d_in[0];
    const int*   ei     = (const int*)d_in[1];
    const float* attr   = (const float*)d_in[2];
    const float* gnn_g  = (const float*)d_in[4];
    const float* gnn_b  = (const float*)d_in[5];
    const float* msg_w1 = (const float*)d_in[6];
    const float* msg_b1 = (const float*)d_in[7];
    const float* msg_w2 = (const float*)d_in[8];
    const float* msg_b2 = (const float*)d_in[9];
    const float* upd_w1 = (const float*)d_in[10];
    const float* upd_b1 = (const float*)d_in[11];
    const float* upd_w2 = (const float*)d_in[12];
    const float* upd_b2 = (const float*)d_in[13];
    const float* in_w   = (const float*)d_in[14];
    const float* in_b   = (const float*)d_in[15];
    const float* out_w  = (const float*)d_in[16];
    const float* out_b  = (const float*)d_in[17];
    const float* ffn_w1 = (const float*)d_in[18];
    const float* ffn_b1 = (const float*)d_in[19];
    const float* ffn_w2 = (const float*)d_in[20];
    const float* ffn_b2 = (const float*)d_in[21];
    const float* n1_g   = (const float*)d_in[22];
    const float* n1_b   = (const float*)d_in[23];
    const float* n2_g   = (const float*)d_in[24];
    const float* n2_b   = (const float*)d_in[25];
    float* out = (float*)d_out;
    float* ws = (float*)d_ws;

    float* xn      = ws;
    float* aggr    = ws + 2097152;
    float* h_local = ws + 4194304;
    float* qkv     = ws + 6291456;   // N*384
    float* o       = ws + 12582912;
    float* h1      = ws + 14680064;

    // edge-phase bf16 buffers overlaid on the (later-written) qkv region
    unsigned short* attr_bf = (unsigned short*)(ws + 6291456);   // E*32 us = 4194304 floats
    unsigned short* xn_bf   = (unsigned short*)(ws + 10485760);  // N*128 us = 1048576 floats
    unsigned short* w1t     = (unsigned short*)(ws + 11534336);  // 256*288 us = 36864 floats
    unsigned short* w2t     = (unsigned short*)(ws + 11571200);  // 128*256 us = 16384 floats

    hipMemsetAsync(aggr, 0, (size_t)N_NODES * DIM * sizeof(float), stream);
    ln_rows_bf<<<N_NODES / 4, 256, 0, stream>>>(x, gnn_g, gnn_b, xn, xn_bf);
    conv_attr<<<(NEDGE * EDIM) / (256 * 8), 256, 0, stream>>>(attr, attr_bf);
    conv_w1t<<<(K1 * H1) / 256, 256, 0, stream>>>(msg_w1, w1t);
    conv_w2t<<<(H1 * DIM) / 256, 256, 0, stream>>>(msg_w2, w2t);
    edge_mlp_mfma<<<NEDGE / EB, 256, 0, stream>>>(xn_bf, ei, attr_bf, w1t, msg_b1, w2t, msg_b2, aggr);
    update_kernel<<<N_NODES, 128, 0, stream>>>(xn, aggr, upd_w1, upd_b1, upd_w2, upd_b2, h_local);
    qkv_kernel<<<N_NODES, 128, 0, stream>>>(x, in_w, in_b, qkv);
    attn_flash<<<NG * NH * 4, 256, 0, stream>>>(qkv, o);
    proj_res_ln<<<N_NODES, 128, 0, stream>>>(x, h_local, o, out_w, out_b, n1_g, n1_b, h1);
    ffn_ln<<<N_NODES, 256, 0, stream>>>(h1, ffn_w1, ffn_b1, ffn_w2, ffn_b2, n2_g, n2_b, out);
}

// Round 5
// 490.985 us; speedup vs baseline: 6.9431x; 1.5883x over previous
//
#include <hip/hip_runtime.h>
#include <cmath>

#define N_NODES 16384
#define DIM 128
#define EDIM 32
#define NEDGE 262144
#define NG 32
#define SEQ 512
#define NH 4
#define HD 32
#define CH 32

#define EB 64
#define K1 288
#define K1P 296
#define H1 256
#define H1P 264
#define HP 136    // 128+8 pad (ushorts)
#define UP 264    // 256+8 pad (ushorts)

typedef __bf16 bf16x8 __attribute__((ext_vector_type(8)));
typedef float f32x4 __attribute__((ext_vector_type(4)));

__device__ __forceinline__ unsigned short f2bf(float f) {
    union { float f; unsigned int u; } v; v.f = f;
    unsigned int r = (v.u + 0x7FFFu + ((v.u >> 16) & 1u)) >> 16;
    return (unsigned short)r;
}
__device__ __forceinline__ float bf2f(unsigned short u) {
    union { unsigned int u; float f; } v; v.u = ((unsigned int)u) << 16;
    return v.f;
}

__device__ __forceinline__ float geluf(float x) {
    return 0.5f * x * (1.0f + erff(x * 0.70710678118654752f));
}

__device__ __forceinline__ float waveSum(float v) {
#pragma unroll
    for (int m = 1; m < 64; m <<= 1) v += __shfl_xor(v, m, 64);
    return v;
}

// --- LN over 128 features -> xn_bf (bf16); also x -> x_bf ---
__global__ __launch_bounds__(256) void ln_rows_bf2(const float* __restrict__ x,
                                                   const float* __restrict__ g,
                                                   const float* __restrict__ b,
                                                   unsigned short* __restrict__ xn_bf,
                                                   unsigned short* __restrict__ x_bf) {
    int wave = threadIdx.x >> 6;
    int lane = threadIdx.x & 63;
    int row = blockIdx.x * 4 + wave;
    const float* xr = x + (size_t)row * DIM;
    float v0 = xr[lane], v1 = xr[lane + 64];
    unsigned short* xbf = x_bf + (size_t)row * DIM;
    xbf[lane] = f2bf(v0);
    xbf[lane + 64] = f2bf(v1);
    float mean = waveSum(v0 + v1) * (1.0f / 128.0f);
    float d0 = v0 - mean, d1 = v1 - mean;
    float var = waveSum(d0 * d0 + d1 * d1) * (1.0f / 128.0f);
    float r = rsqrtf(var + 1e-5f);
    unsigned short* obf = xn_bf + (size_t)row * DIM;
    obf[lane] = f2bf(d0 * r * g[lane] + b[lane]);
    obf[lane + 64] = f2bf(d1 * r * g[lane + 64] + b[lane + 64]);
}

// --- attr f32 -> bf16 ---
__global__ __launch_bounds__(256) void conv_attr(const float* __restrict__ a,
                                                 unsigned short* __restrict__ abf) {
    size_t i = ((size_t)blockIdx.x * 256 + threadIdx.x) * 8;
    float4 x0 = *(const float4*)&a[i];
    float4 x1 = *(const float4*)&a[i + 4];
    unsigned short r[8];
    r[0] = f2bf(x0.x); r[1] = f2bf(x0.y); r[2] = f2bf(x0.z); r[3] = f2bf(x0.w);
    r[4] = f2bf(x1.x); r[5] = f2bf(x1.y); r[6] = f2bf(x1.z); r[7] = f2bf(x1.w);
    *(uint4*)&abf[i] = *(const uint4*)r;
}

// --- all 8 weight transposes+conversions fused ---
__global__ __launch_bounds__(256) void conv_weights(
    const float* __restrict__ s0, const float* __restrict__ s1,
    const float* __restrict__ s2, const float* __restrict__ s3,
    const float* __restrict__ s4, const float* __restrict__ s5,
    const float* __restrict__ s6, const float* __restrict__ s7,
    unsigned short* __restrict__ d0, unsigned short* __restrict__ d1,
    unsigned short* __restrict__ d2, unsigned short* __restrict__ d3,
    unsigned short* __restrict__ d4, unsigned short* __restrict__ d5,
    unsigned short* __restrict__ d6, unsigned short* __restrict__ d7) {
    int i = blockIdx.x * 256 + threadIdx.x;
    if (i < 73728)        { int k = i >> 8, n = i & 255;                 d0[n * 288 + k] = f2bf(s0[i]); }
    else if (i < 106496)  { int j = i - 73728;  int k = j >> 7, n = j & 127; d1[n * 256 + k] = f2bf(s1[j]); }
    else if (i < 139264)  { int j = i - 106496; int k = j >> 7, n = j & 127; d2[n * 256 + k] = f2bf(s2[j]); }
    else if (i < 155648)  { int j = i - 139264; int k = j >> 7, n = j & 127; d3[n * 128 + k] = f2bf(s3[j]); }
    else if (i < 204800)  { int j = i - 155648; int k = j / 384, n = j - k * 384; d4[n * 128 + k] = f2bf(s4[j]); }
    else if (i < 221184)  { int j = i - 204800; int k = j >> 7, n = j & 127; d5[n * 128 + k] = f2bf(s5[j]); }
    else if (i < 253952)  { int j = i - 221184; int k = j >> 8, n = j & 255; d6[n * 128 + k] = f2bf(s6[j]); }
    else if (i < 286720)  { int j = i - 253952; int k = j >> 7, n = j & 127; d7[n * 256 + k] = f2bf(s7[j]); }
}

// --- edge MLP with bf16 MFMA (unchanged from round 4) ---
__global__ __launch_bounds__(256, 2) void edge_mlp_mfma(const unsigned short* __restrict__ xn_bf,
                                                        const int* __restrict__ ei,
                                                        const unsigned short* __restrict__ attr_bf,
                                                        const unsigned short* __restrict__ w1t,
                                                        const float* __restrict__ b1,
                                                        const unsigned short* __restrict__ w2t,
                                                        const float* __restrict__ b2,
                                                        float* __restrict__ aggr) {
    __shared__ __align__(16) unsigned short in_s[EB][K1P];
    __shared__ __align__(16) unsigned short h_s[EB][H1P];
    __shared__ int ds[EB], ss[EB];
    int t = threadIdx.x;
    int eb0 = blockIdx.x * EB;
    if (t < EB) ds[t] = ei[NEDGE + eb0 + t];
    else if (t < 2 * EB) ss[t - EB] = ei[eb0 + t - EB];
    __syncthreads();
    for (int idx = t; idx < EB * 36; idx += 256) {
        int e = idx / 36;
        int seg = idx - e * 36;
        const unsigned short* src;
        if (seg < 16)      src = xn_bf + (size_t)ds[e] * DIM + seg * 8;
        else if (seg < 32) src = xn_bf + (size_t)ss[e] * DIM + (seg - 16) * 8;
        else               src = attr_bf + (size_t)(eb0 + e) * EDIM + (seg - 32) * 8;
        *(uint4*)&in_s[e][seg * 8] = *(const uint4*)src;
    }
    __syncthreads();

    int w = t >> 6;
    int lane = t & 63;
    int l15 = lane & 15;
    int kq = lane >> 4;

    f32x4 acc[4][4] = {};
    for (int kk = 0; kk < 9; ++kk) {
        bf16x8 a[4], bw[4];
#pragma unroll
        for (int mi = 0; mi < 4; ++mi)
            a[mi] = *(const bf16x8*)&in_s[mi * 16 + l15][kk * 32 + kq * 8];
#pragma unroll
        for (int ni = 0; ni < 4; ++ni)
            bw[ni] = *(const bf16x8*)&w1t[(size_t)((w << 6) + ni * 16 + l15) * K1 + kk * 32 + kq * 8];
#pragma unroll
        for (int mi = 0; mi < 4; ++mi)
#pragma unroll
            for (int ni = 0; ni < 4; ++ni)
                acc[mi][ni] = __builtin_amdgcn_mfma_f32_16x16x32_bf16(a[mi], bw[ni], acc[mi][ni], 0, 0, 0);
    }
#pragma unroll
    for (int mi = 0; mi < 4; ++mi)
#pragma unroll
        for (int ni = 0; ni < 4; ++ni) {
            int col = (w << 6) + ni * 16 + l15;
            float bias = b1[col];
#pragma unroll
            for (int j = 0; j < 4; ++j) {
                int row = mi * 16 + kq * 4 + j;
                h_s[row][col] = f2bf(geluf(acc[mi][ni][j] + bias));
            }
        }
    __syncthreads();

    f32x4 acc2[4][2] = {};
    for (int kk = 0; kk < 8; ++kk) {
        bf16x8 a2[4], bw2[2];
#pragma unroll
        for (int mi = 0; mi < 4; ++mi)
            a2[mi] = *(const bf16x8*)&h_s[mi * 16 + l15][kk * 32 + kq * 8];
#pragma unroll
        for (int ni = 0; ni < 2; ++ni)
            bw2[ni] = *(const bf16x8*)&w2t[(size_t)((w << 5) + ni * 16 + l15) * H1 + kk * 32 + kq * 8];
#pragma unroll
        for (int mi = 0; mi < 4; ++mi)
#pragma unroll
            for (int ni = 0; ni < 2; ++ni)
                acc2[mi][ni] = __builtin_amdgcn_mfma_f32_16x16x32_bf16(a2[mi], bw2[ni], acc2[mi][ni], 0, 0, 0);
    }
#pragma unroll
    for (int mi = 0; mi < 4; ++mi)
#pragma unroll
        for (int ni = 0; ni < 2; ++ni) {
            int col = (w << 5) + ni * 16 + l15;
            float bias = b2[col];
#pragma unroll
            for (int j = 0; j < 4; ++j) {
                int row = mi * 16 + kq * 4 + j;
                atomicAdd(&aggr[(size_t)ds[row] * DIM + col], acc2[mi][ni][j] + bias);
            }
        }
}

// --- node update MLP, MFMA: h_local = gelu([xn|aggr] @ U1 + b1) @ U2 + b2 ---
__global__ __launch_bounds__(256, 2) void update_mfma(const unsigned short* __restrict__ xn_bf,
                                                      const float* __restrict__ aggr,
                                                      const unsigned short* __restrict__ uw1t,
                                                      const float* __restrict__ b1,
                                                      const unsigned short* __restrict__ uw2t,
                                                      const float* __restrict__ b2,
                                                      float* __restrict__ h_local) {
    __shared__ __align__(16) unsigned short cat_s[64][UP];
    __shared__ __align__(16) unsigned short hu_s[64][HP];
    int t = threadIdx.x;
    int n0 = blockIdx.x * 64;
    for (int idx = t; idx < 64 * 32; idx += 256) {
        int e = idx >> 5, seg = idx & 31;
        if (seg < 16) {
            *(uint4*)&cat_s[e][seg * 8] = *(const uint4*)&xn_bf[(size_t)(n0 + e) * DIM + seg * 8];
        } else {
            const float* src = &aggr[(size_t)(n0 + e) * DIM + (seg - 16) * 8];
            float4 a0 = *(const float4*)src, a1 = *(const float4*)(src + 4);
            unsigned short r[8] = {f2bf(a0.x), f2bf(a0.y), f2bf(a0.z), f2bf(a0.w),
                                   f2bf(a1.x), f2bf(a1.y), f2bf(a1.z), f2bf(a1.w)};
            *(uint4*)&cat_s[e][128 + (seg - 16) * 8] = *(const uint4*)r;
        }
    }
    __syncthreads();
    int w = t >> 6, lane = t & 63, l15 = lane & 15, kq = lane >> 4;

    f32x4 acc[4][2] = {};
    for (int kk = 0; kk < 8; ++kk) {
        bf16x8 a[4], bw[2];
#pragma unroll
        for (int mi = 0; mi < 4; ++mi)
            a[mi] = *(const bf16x8*)&cat_s[mi * 16 + l15][kk * 32 + kq * 8];
#pragma unroll
        for (int ni = 0; ni < 2; ++ni)
            bw[ni] = *(const bf16x8*)&uw1t[(size_t)((w << 5) + ni * 16 + l15) * 256 + kk * 32 + kq * 8];
#pragma unroll
        for (int mi = 0; mi < 4; ++mi)
#pragma unroll
            for (int ni = 0; ni < 2; ++ni)
                acc[mi][ni] = __builtin_amdgcn_mfma_f32_16x16x32_bf16(a[mi], bw[ni], acc[mi][ni], 0, 0, 0);
    }
#pragma unroll
    for (int mi = 0; mi < 4; ++mi)
#pragma unroll
        for (int ni = 0; ni < 2; ++ni) {
            int col = (w << 5) + ni * 16 + l15;
            float bias = b1[col];
#pragma unroll
            for (int j = 0; j < 4; ++j) {
                int row = mi * 16 + kq * 4 + j;
                hu_s[row][col] = f2bf(geluf(acc[mi][ni][j] + bias));
            }
        }
    __syncthreads();

    f32x4 acc2[4][2] = {};
    for (int kk = 0; kk < 4; ++kk) {
        bf16x8 a2[4], bw2[2];
#pragma unroll
        for (int mi = 0; mi < 4; ++mi)
            a2[mi] = *(const bf16x8*)&hu_s[mi * 16 + l15][kk * 32 + kq * 8];
#pragma unroll
        for (int ni = 0; ni < 2; ++ni)
            bw2[ni] = *(const bf16x8*)&uw2t[(size_t)((w << 5) + ni * 16 + l15) * 128 + kk * 32 + kq * 8];
#pragma unroll
        for (int mi = 0; mi < 4; ++mi)
#pragma unroll
            for (int ni = 0; ni < 2; ++ni)
                acc2[mi][ni] = __builtin_amdgcn_mfma_f32_16x16x32_bf16(a2[mi], bw2[ni], acc2[mi][ni], 0, 0, 0);
    }
#pragma unroll
    for (int mi = 0; mi < 4; ++mi)
#pragma unroll
        for (int ni = 0; ni < 2; ++ni) {
            int col = (w << 5) + ni * 16 + l15;
            float bias = b2[col];
#pragma unroll
            for (int j = 0; j < 4; ++j) {
                int row = mi * 16 + kq * 4 + j;
                h_local[(size_t)(n0 + row) * DIM + col] = acc2[mi][ni][j] + bias;
            }
        }
}

// --- qkv = x @ in_w + in_b (bf16 out), MFMA ---
__global__ __launch_bounds__(256, 2) void qkv_mfma(const unsigned short* __restrict__ x_bf,
                                                   const unsigned short* __restrict__ iwt,
                                                   const float* __restrict__ b,
                                                   unsigned short* __restrict__ qkv_bf) {
    __shared__ __align__(16) unsigned short x_s[64][HP];
    int t = threadIdx.x;
    int n0 = blockIdx.x * 64;
    for (int idx = t; idx < 64 * 16; idx += 256) {
        int e = idx >> 4, seg = idx & 15;
        *(uint4*)&x_s[e][seg * 8] = *(const uint4*)&x_bf[(size_t)(n0 + e) * DIM + seg * 8];
    }
    __syncthreads();
    int w = t >> 6, lane = t & 63, l15 = lane & 15, kq = lane >> 4;

    f32x4 acc[4][6] = {};
    for (int kk = 0; kk < 4; ++kk) {
        bf16x8 a[4], bw[6];
#pragma unroll
        for (int mi = 0; mi < 4; ++mi)
            a[mi] = *(const bf16x8*)&x_s[mi * 16 + l15][kk * 32 + kq * 8];
#pragma unroll
        for (int ni = 0; ni < 6; ++ni)
            bw[ni] = *(const bf16x8*)&iwt[(size_t)(w * 96 + ni * 16 + l15) * 128 + kk * 32 + kq * 8];
#pragma unroll
        for (int mi = 0; mi < 4; ++mi)
#pragma unroll
            for (int ni = 0; ni < 6; ++ni)
                acc[mi][ni] = __builtin_amdgcn_mfma_f32_16x16x32_bf16(a[mi], bw[ni], acc[mi][ni], 0, 0, 0);
    }
#pragma unroll
    for (int mi = 0; mi < 4; ++mi)
#pragma unroll
        for (int ni = 0; ni < 6; ++ni) {
            int col = w * 96 + ni * 16 + l15;
            float bias = b[col];
#pragma unroll
            for (int j = 0; j < 4; ++j) {
                int row = mi * 16 + kq * 4 + j;
                qkv_bf[(size_t)(n0 + row) * 384 + col] = f2bf(acc[mi][ni][j] + bias);
            }
        }
}

// --- flash attention on bf16 qkv ---
__global__ __launch_bounds__(256) void attn_flash(const unsigned short* __restrict__ qkv,
                                                  float* __restrict__ o) {
    int bid = blockIdx.x;
    int quarter = bid & 3;
    int h = (bid >> 2) & 3;
    int g = bid >> 4;
    int t = threadIdx.x;
    int qi = t & 127;
    int sp = t >> 7;
    int sq = quarter * 128 + qi;
    int nq = g * SEQ + sq;

    __shared__ __align__(16) float k_s[2][CH][HD];
    __shared__ __align__(16) float v_s[2][CH][HD];
    __shared__ float merge_s[128][34];

    float qv[HD];
    const unsigned short* qr = qkv + (size_t)nq * 384 + h * HD;
#pragma unroll
    for (int d0 = 0; d0 < HD; d0 += 8) {
        uint4 raw = *(const uint4*)&qr[d0];
        const unsigned short* rs = (const unsigned short*)&raw;
#pragma unroll
        for (int j = 0; j < 8; ++j) qv[d0 + j] = bf2f(rs[j]);
    }
    const float scale = 0.17677669529663687f;
#pragma unroll
    for (int d = 0; d < HD; ++d) qv[d] *= scale;

    float m = -1e30f, l = 0.0f;
    float oacc[HD];
#pragma unroll
    for (int d = 0; d < HD; ++d) oacc[d] = 0.0f;

    int base_j = sp * 256;
    int r = qi >> 3;
    int c4 = (qi & 7) * 4;
    for (int c0 = 0; c0 < 256; c0 += CH) {
        __syncthreads();
#pragma unroll
        for (int p = 0; p < CH; p += 16) {
            int j = base_j + c0 + p + r;
            const unsigned short* kr = qkv + (size_t)(g * SEQ + j) * 384 + 128 + h * HD;
            const unsigned short* vr = qkv + (size_t)(g * SEQ + j) * 384 + 256 + h * HD;
            uint2 kraw = *(const uint2*)&kr[c4];
            uint2 vraw = *(const uint2*)&vr[c4];
            const unsigned short* kp = (const unsigned short*)&kraw;
            const unsigned short* vp = (const unsigned short*)&vraw;
            float4 kf = {bf2f(kp[0]), bf2f(kp[1]), bf2f(kp[2]), bf2f(kp[3])};
            float4 vf = {bf2f(vp[0]), bf2f(vp[1]), bf2f(vp[2]), bf2f(vp[3])};
            *(float4*)&k_s[sp][p + r][c4] = kf;
            *(float4*)&v_s[sp][p + r][c4] = vf;
        }
        __syncthreads();
        float sc[CH];
#pragma unroll
        for (int j = 0; j < CH; ++j) {
            float s = 0.0f;
#pragma unroll
            for (int d = 0; d < HD; ++d) s = fmaf(qv[d], k_s[sp][j][d], s);
            sc[j] = s;
        }
        float cm = sc[0];
#pragma unroll
        for (int j = 1; j < CH; ++j) cm = fmaxf(cm, sc[j]);
        float mn = fmaxf(m, cm);
        float corr = __expf(m - mn);
        l *= corr;
#pragma unroll
        for (int d = 0; d < HD; ++d) oacc[d] *= corr;
#pragma unroll
        for (int j = 0; j < CH; ++j) {
            float p = __expf(sc[j] - mn);
            l += p;
#pragma unroll
            for (int d = 0; d < HD; ++d) oacc[d] = fmaf(p, v_s[sp][j][d], oacc[d]);
        }
        m = mn;
    }
    __syncthreads();
    if (sp == 1) {
        merge_s[qi][0] = m;
        merge_s[qi][1] = l;
#pragma unroll
        for (int d = 0; d < HD; ++d) merge_s[qi][2 + d] = oacc[d];
    }
    __syncthreads();
    if (sp == 0) {
        float m1 = merge_s[qi][0], l1 = merge_s[qi][1];
        float mn = fmaxf(m, m1);
        float cc0 = __expf(m - mn), cc1 = __expf(m1 - mn);
        float inv = 1.0f / (cc0 * l + cc1 * l1);
        float* orow = o + (size_t)nq * DIM + h * HD;
#pragma unroll
        for (int d = 0; d < HD; ++d)
            orow[d] = (cc0 * oacc[d] + cc1 * merge_s[qi][2 + d]) * inv;
    }
}

// --- h1 = LN1(x + h_local + o @ out_w + out_b), MFMA + fused LN ---
__global__ __launch_bounds__(256, 2) void proj_res_ln_mfma(const float* __restrict__ x,
                                                           const float* __restrict__ h_local,
                                                           const float* __restrict__ o,
                                                           const unsigned short* __restrict__ owt,
                                                           const float* __restrict__ ob,
                                                           const float* __restrict__ g1,
                                                           const float* __restrict__ bb1,
                                                           float* __restrict__ h1) {
    __shared__ __align__(16) unsigned short o_s[64][HP];
    __shared__ float y_s[64][132];
    int t = threadIdx.x;
    int n0 = blockIdx.x * 64;
    for (int idx = t; idx < 64 * 16; idx += 256) {
        int e = idx >> 4, seg = idx & 15;
        const float* src = &o[(size_t)(n0 + e) * DIM + seg * 8];
        float4 a0 = *(const float4*)src, a1 = *(const float4*)(src + 4);
        unsigned short rr[8] = {f2bf(a0.x), f2bf(a0.y), f2bf(a0.z), f2bf(a0.w),
                                f2bf(a1.x), f2bf(a1.y), f2bf(a1.z), f2bf(a1.w)};
        *(uint4*)&o_s[e][seg * 8] = *(const uint4*)rr;
    }
    __syncthreads();
    int w = t >> 6, lane = t & 63, l15 = lane & 15, kq = lane >> 4;

    f32x4 acc[4][2] = {};
    for (int kk = 0; kk < 4; ++kk) {
        bf16x8 a[4], bw[2];
#pragma unroll
        for (int mi = 0; mi < 4; ++mi)
            a[mi] = *(const bf16x8*)&o_s[mi * 16 + l15][kk * 32 + kq * 8];
#pragma unroll
        for (int ni = 0; ni < 2; ++ni)
            bw[ni] = *(const bf16x8*)&owt[(size_t)((w << 5) + ni * 16 + l15) * 128 + kk * 32 + kq * 8];
#pragma unroll
        for (int mi = 0; mi < 4; ++mi)
#pragma unroll
            for (int ni = 0; ni < 2; ++ni)
                acc[mi][ni] = __builtin_amdgcn_mfma_f32_16x16x32_bf16(a[mi], bw[ni], acc[mi][ni], 0, 0, 0);
    }
#pragma unroll
    for (int mi = 0; mi < 4; ++mi)
#pragma unroll
        for (int ni = 0; ni < 2; ++ni) {
            int col = (w << 5) + ni * 16 + l15;
            float bias = ob[col];
#pragma unroll
            for (int j = 0; j < 4; ++j) {
                int row = mi * 16 + kq * 4 + j;
                size_t gi = (size_t)(n0 + row) * DIM + col;
                y_s[row][col] = x[gi] + h_local[gi] + acc[mi][ni][j] + bias;
            }
        }
    __syncthreads();
    for (int rr = 0; rr < 16; ++rr) {
        int row = (w << 4) + rr;
        float v0 = y_s[row][lane], v1 = y_s[row][lane + 64];
        float mean = waveSum(v0 + v1) * (1.0f / 128.0f);
        float d0 = v0 - mean, d1 = v1 - mean;
        float var = waveSum(d0 * d0 + d1 * d1) * (1.0f / 128.0f);
        float rs = rsqrtf(var + 1e-5f);
        float* hrow = h1 + (size_t)(n0 + row) * DIM;
        hrow[lane] = d0 * rs * g1[lane] + bb1[lane];
        hrow[lane + 64] = d1 * rs * g1[lane + 64] + bb1[lane + 64];
    }
}

// --- out = LN2(h1 + gelu(h1 @ F1 + fb1) @ F2 + fb2), MFMA + fused LN ---
__global__ __launch_bounds__(256, 1) void ffn_ln_mfma(const float* __restrict__ h1,
                                                      const unsigned short* __restrict__ fw1t,
                                                      const float* __restrict__ fb1,
                                                      const unsigned short* __restrict__ fw2t,
                                                      const float* __restrict__ fb2,
                                                      const float* __restrict__ g2,
                                                      const float* __restrict__ b2n,
                                                      float* __restrict__ out) {
    __shared__ __align__(16) unsigned short h_s[64][HP];
    __shared__ __align__(16) unsigned short hid_s[64][UP];
    __shared__ float y_s[64][132];
    int t = threadIdx.x;
    int n0 = blockIdx.x * 64;
    for (int idx = t; idx < 64 * 16; idx += 256) {
        int e = idx >> 4, seg = idx & 15;
        const float* src = &h1[(size_t)(n0 + e) * DIM + seg * 8];
        float4 a0 = *(const float4*)src, a1 = *(const float4*)(src + 4);
        unsigned short rr[8] = {f2bf(a0.x), f2bf(a0.y), f2bf(a0.z), f2bf(a0.w),
                                f2bf(a1.x), f2bf(a1.y), f2bf(a1.z), f2bf(a1.w)};
        *(uint4*)&h_s[e][seg * 8] = *(const uint4*)rr;
    }
    __syncthreads();
    int w = t >> 6, lane = t & 63, l15 = lane & 15, kq = lane >> 4;

    f32x4 acc[4][4] = {};
    for (int kk = 0; kk < 4; ++kk) {
        bf16x8 a[4], bw[4];
#pragma unroll
        for (int mi = 0; mi < 4; ++mi)
            a[mi] = *(const bf16x8*)&h_s[mi * 16 + l15][kk * 32 + kq * 8];
#pragma unroll
        for (int ni = 0; ni < 4; ++ni)
            bw[ni] = *(const bf16x8*)&fw1t[(size_t)((w << 6) + ni * 16 + l15) * 128 + kk * 32 + kq * 8];
#pragma unroll
        for (int mi = 0; mi < 4; ++mi)
#pragma unroll
            for (int ni = 0; ni < 4; ++ni)
                acc[mi][ni] = __builtin_amdgcn_mfma_f32_16x16x32_bf16(a[mi], bw[ni], acc[mi][ni], 0, 0, 0);
    }
#pragma unroll
    for (int mi = 0; mi < 4; ++mi)
#pragma unroll
        for (int ni = 0; ni < 4; ++ni) {
            int col = (w << 6) + ni * 16 + l15;
            float bias = fb1[col];
#pragma unroll
            for (int j = 0; j < 4; ++j) {
                int row = mi * 16 + kq * 4 + j;
                hid_s[row][col] = f2bf(geluf(acc[mi][ni][j] + bias));
            }
        }
    __syncthreads();

    f32x4 acc2[4][2] = {};
    for (int kk = 0; kk < 8; ++kk) {
        bf16x8 a2[4], bw2[2];
#pragma unroll
        for (int mi = 0; mi < 4; ++mi)
            a2[mi] = *(const bf16x8*)&hid_s[mi * 16 + l15][kk * 32 + kq * 8];
#pragma unroll
        for (int ni = 0; ni < 2; ++ni)
            bw2[ni] = *(const bf16x8*)&fw2t[(size_t)((w << 5) + ni * 16 + l15) * 256 + kk * 32 + kq * 8];
#pragma unroll
        for (int mi = 0; mi < 4; ++mi)
#pragma unroll
            for (int ni = 0; ni < 2; ++ni)
                acc2[mi][ni] = __builtin_amdgcn_mfma_f32_16x16x32_bf16(a2[mi], bw2[ni], acc2[mi][ni], 0, 0, 0);
    }
#pragma unroll
    for (int mi = 0; mi < 4; ++mi)
#pragma unroll
        for (int ni = 0; ni < 2; ++ni) {
            int col = (w << 5) + ni * 16 + l15;
            float bias = fb2[col];
#pragma unroll
            for (int j = 0; j < 4; ++j) {
                int row = mi * 16 + kq * 4 + j;
                y_s[row][col] = h1[(size_t)(n0 + row) * DIM + col] + acc2[mi][ni][j] + bias;
            }
        }
    __syncthreads();
    for (int rr = 0; rr < 16; ++rr) {
        int row = (w << 4) + rr;
        float v0 = y_s[row][lane], v1 = y_s[row][lane + 64];
        float mean = waveSum(v0 + v1) * (1.0f / 128.0f);
        float d0 = v0 - mean, d1 = v1 - mean;
        float var = waveSum(d0 * d0 + d1 * d1) * (1.0f / 128.0f);
        float rs = rsqrtf(var + 1e-5f);
        float* orow = out + (size_t)(n0 + row) * DIM;
        orow[lane] = d0 * rs * g2[lane] + b2n[lane];
        orow[lane + 64] = d1 * rs * g2[lane + 64] + b2n[lane + 64];
    }
}

extern "C" void kernel_launch(void* const* d_in, const int* in_sizes, int n_in,
                              void* d_out, int out_size, void* d_ws, size_t ws_size,
                              hipStream_t stream) {
    const float* x      = (const float*)d_in[0];
    const int*   ei     = (const int*)d_in[1];
    const float* attr   = (const float*)d_in[2];
    const float* gnn_g  = (const float*)d_in[4];
    const float* gnn_b  = (const float*)d_in[5];
    const float* msg_w1 = (const float*)d_in[6];
    const float* msg_b1 = (const float*)d_in[7];
    const float* msg_w2 = (const float*)d_in[8];
    const float* msg_b2 = (const float*)d_in[9];
    const float* upd_w1 = (const float*)d_in[10];
    const float* upd_b1 = (const float*)d_in[11];
    const float* upd_w2 = (const float*)d_in[12];
    const float* upd_b2 = (const float*)d_in[13];
    const float* in_w   = (const float*)d_in[14];
    const float* in_b   = (const float*)d_in[15];
    const float* out_w  = (const float*)d_in[16];
    const float* out_b  = (const float*)d_in[17];
    const float* ffn_w1 = (const float*)d_in[18];
    const float* ffn_b1 = (const float*)d_in[19];
    const float* ffn_w2 = (const float*)d_in[20];
    const float* ffn_b2 = (const float*)d_in[21];
    const float* n1_g   = (const float*)d_in[22];
    const float* n1_b   = (const float*)d_in[23];
    const float* n2_g   = (const float*)d_in[24];
    const float* n2_b   = (const float*)d_in[25];
    float* out = (float*)d_out;
    float* ws = (float*)d_ws;

    // layout (float offsets), total = 16,777,216 floats = 64 MB
    float* aggr    = ws;                                         // 2,097,152
    float* h_local = ws + 2097152;                               // 2,097,152
    unsigned short* qkv_bf = (unsigned short*)(ws + 4194304);    // N*384 us = 1,572,864 fl
    float* o       = ws + 5767168;                               // 2,097,152
    float* h1      = ws + 7864320;                               // 2,097,152
    unsigned short* xn_bf  = (unsigned short*)(ws + 9961472);    // 1,048,576 fl
    unsigned short* x_bf   = (unsigned short*)(ws + 11010048);   // 1,048,576 fl
    unsigned short* w1t    = (unsigned short*)(ws + 12058624);   // 36,864 fl
    unsigned short* w2t    = (unsigned short*)(ws + 12095488);   // 16,384 fl
    unsigned short* uw1t   = (unsigned short*)(ws + 12111872);   // 16,384 fl
    unsigned short* uw2t   = (unsigned short*)(ws + 12128256);   // 8,192 fl
    unsigned short* iwt    = (unsigned short*)(ws + 12136448);   // 24,576 fl
    unsigned short* owt    = (unsigned short*)(ws + 12161024);   // 8,192 fl
    unsigned short* fw1t   = (unsigned short*)(ws + 12169216);   // 16,384 fl
    unsigned short* fw2t   = (unsigned short*)(ws + 12185600);   // 16,384 fl
    unsigned short* attr_bf = (unsigned short*)(ws + 12582912);  // 4,194,304 fl

    hipMemsetAsync(aggr, 0, (size_t)N_NODES * DIM * sizeof(float), stream);
    ln_rows_bf2<<<N_NODES / 4, 256, 0, stream>>>(x, gnn_g, gnn_b, xn_bf, x_bf);
    conv_attr<<<(NEDGE * EDIM) / (256 * 8), 256, 0, stream>>>(attr, attr_bf);
    conv_weights<<<1120, 256, 0, stream>>>(msg_w1, msg_w2, upd_w1, upd_w2, in_w, out_w, ffn_w1, ffn_w2,
                                           w1t, w2t, uw1t, uw2t, iwt, owt, fw1t, fw2t);
    edge_mlp_mfma<<<NEDGE / EB, 256, 0, stream>>>(xn_bf, ei, attr_bf, w1t, msg_b1, w2t, msg_b2, aggr);
    update_mfma<<<N_NODES / 64, 256, 0, stream>>>(xn_bf, aggr, uw1t, upd_b1, uw2t, upd_b2, h_local);
    qkv_mfma<<<N_NODES / 64, 256, 0, stream>>>(x_bf, iwt, in_b, qkv_bf);
    attn_flash<<<NG * NH * 4, 256, 0, stream>>>(qkv_bf, o);
    proj_res_ln_mfma<<<N_NODES / 64, 256, 0, stream>>>(x, h_local, o, owt, out_b, n1_g, n1_b, h1);
    ffn_ln_mfma<<<N_NODES / 64, 256, 0, stream>>>(h1, fw1t, ffn_b1, fw2t, ffn_b2, n2_g, n2_b, out);
}

// Round 8
// 462.628 us; speedup vs baseline: 7.3687x; 1.0613x over previous
//
#include <hip/hip_runtime.h>
#include <cmath>

#define N_NODES 16384
#define DIM 128
#define EDIM 32
#define NEDGE 262144
#define NG 32
#define SEQ 512
#define NH 4
#define HD 32
#define CH 32

#define EB 32
#define K1 288
#define K1P 296
#define H1 256
#define H1P 264
#define HP 136    // 128+8 pad (ushorts)
#define UP 264    // 256+8 pad (ushorts)

typedef __bf16 bf16x8 __attribute__((ext_vector_type(8)));
typedef float f32x4 __attribute__((ext_vector_type(4)));

__device__ __forceinline__ unsigned short f2bf(float f) {
    union { float f; unsigned int u; } v; v.f = f;
    unsigned int r = (v.u + 0x7FFFu + ((v.u >> 16) & 1u)) >> 16;
    return (unsigned short)r;
}
__device__ __forceinline__ float bf2f(unsigned short u) {
    union { unsigned int u; float f; } v; v.u = ((unsigned int)u) << 16;
    return v.f;
}

// tanh-approx gelu: max |diff| vs erf-gelu ~3e-3, no branches, 1 exp
__device__ __forceinline__ float geluf(float x) {
    float z = 0.7978845608f * (x + 0.044715f * x * x * x);
    float e = __expf(2.0f * z);
    float t = 1.0f - 2.0f / (e + 1.0f);
    return 0.5f * x * (1.0f + t);
}

__device__ __forceinline__ float waveSum(float v) {
#pragma unroll
    for (int m = 1; m < 64; m <<= 1) v += __shfl_xor(v, m, 64);
    return v;
}

// --- LN over 128 features -> xn_bf (bf16); also x -> x_bf ---
__global__ __launch_bounds__(256) void ln_rows_bf2(const float* __restrict__ x,
                                                   const float* __restrict__ g,
                                                   const float* __restrict__ b,
                                                   unsigned short* __restrict__ xn_bf,
                                                   unsigned short* __restrict__ x_bf) {
    int wave = threadIdx.x >> 6;
    int lane = threadIdx.x & 63;
    int row = blockIdx.x * 4 + wave;
    const float* xr = x + (size_t)row * DIM;
    float v0 = xr[lane], v1 = xr[lane + 64];
    unsigned short* xbf = x_bf + (size_t)row * DIM;
    xbf[lane] = f2bf(v0);
    xbf[lane + 64] = f2bf(v1);
    float mean = waveSum(v0 + v1) * (1.0f / 128.0f);
    float d0 = v0 - mean, d1 = v1 - mean;
    float var = waveSum(d0 * d0 + d1 * d1) * (1.0f / 128.0f);
    float r = rsqrtf(var + 1e-5f);
    unsigned short* obf = xn_bf + (size_t)row * DIM;
    obf[lane] = f2bf(d0 * r * g[lane] + b[lane]);
    obf[lane + 64] = f2bf(d1 * r * g[lane + 64] + b[lane + 64]);
}

// --- attr f32 -> bf16 ---
__global__ __launch_bounds__(256) void conv_attr(const float* __restrict__ a,
                                                 unsigned short* __restrict__ abf) {
    size_t i = ((size_t)blockIdx.x * 256 + threadIdx.x) * 8;
    float4 x0 = *(const float4*)&a[i];
    float4 x1 = *(const float4*)&a[i + 4];
    unsigned short r[8];
    r[0] = f2bf(x0.x); r[1] = f2bf(x0.y); r[2] = f2bf(x0.z); r[3] = f2bf(x0.w);
    r[4] = f2bf(x1.x); r[5] = f2bf(x1.y); r[6] = f2bf(x1.z); r[7] = f2bf(x1.w);
    *(uint4*)&abf[i] = *(const uint4*)r;
}

// --- all 8 weight transposes+conversions fused ---
__global__ __launch_bounds__(256) void conv_weights(
    const float* __restrict__ s0, const float* __restrict__ s1,
    const float* __restrict__ s2, const float* __restrict__ s3,
    const float* __restrict__ s4, const float* __restrict__ s5,
    const float* __restrict__ s6, const float* __restrict__ s7,
    unsigned short* __restrict__ d0, unsigned short* __restrict__ d1,
    unsigned short* __restrict__ d2, unsigned short* __restrict__ d3,
    unsigned short* __restrict__ d4, unsigned short* __restrict__ d5,
    unsigned short* __restrict__ d6, unsigned short* __restrict__ d7) {
    int i = blockIdx.x * 256 + threadIdx.x;
    if (i < 73728)        { int k = i >> 8, n = i & 255;                 d0[n * 288 + k] = f2bf(s0[i]); }
    else if (i < 106496)  { int j = i - 73728;  int k = j >> 7, n = j & 127; d1[n * 256 + k] = f2bf(s1[j]); }
    else if (i < 139264)  { int j = i - 106496; int k = j >> 7, n = j & 127; d2[n * 256 + k] = f2bf(s2[j]); }
    else if (i < 155648)  { int j = i - 139264; int k = j >> 7, n = j & 127; d3[n * 128 + k] = f2bf(s3[j]); }
    else if (i < 204800)  { int j = i - 155648; int k = j / 384, n = j - k * 384; d4[n * 128 + k] = f2bf(s4[j]); }
    else if (i < 221184)  { int j = i - 204800; int k = j >> 7, n = j & 127; d5[n * 128 + k] = f2bf(s5[j]); }
    else if (i < 253952)  { int j = i - 221184; int k = j >> 8, n = j & 255; d6[n * 128 + k] = f2bf(s6[j]); }
    else if (i < 286720)  { int j = i - 253952; int k = j >> 7, n = j & 127; d7[n * 256 + k] = f2bf(s7[j]); }
}

// --- edge MLP, bf16 MFMA: 32 edges/block, 4 waves, 4 blocks/CU ---
__global__ __launch_bounds__(256, 4) void edge_mlp_mfma(const unsigned short* __restrict__ xn_bf,
                                                        const int* __restrict__ ei,
                                                        const unsigned short* __restrict__ attr_bf,
                                                        const unsigned short* __restrict__ w1t,
                                                        const float* __restrict__ b1,
                                                        const unsigned short* __restrict__ w2t,
                                                        const float* __restrict__ b2,
                                                        float* __restrict__ aggr) {
    __shared__ __align__(16) unsigned short in_s[EB][K1P];  // 18944 B
    __shared__ __align__(16) unsigned short h_s[EB][H1P];   // 16896 B
    __shared__ int ds[EB], ss[EB];
    int t = threadIdx.x;
    int eb0 = blockIdx.x * EB;
    if (t < EB) ds[t] = ei[NEDGE + eb0 + t];
    else if (t < 2 * EB) ss[t - EB] = ei[eb0 + t - EB];
    __syncthreads();
    // stage IN = [xn[dst] | xn[src] | attr], 36 x 16B per edge
    for (int idx = t; idx < EB * 36; idx += 256) {
        int e = idx / 36;
        int seg = idx - e * 36;
        const unsigned short* src;
        if (seg < 16)      src = xn_bf + (size_t)ds[e] * DIM + seg * 8;
        else if (seg < 32) src = xn_bf + (size_t)ss[e] * DIM + (seg - 16) * 8;
        else               src = attr_bf + (size_t)(eb0 + e) * EDIM + (seg - 32) * 8;
        *(uint4*)&in_s[e][seg * 8] = *(const uint4*)src;
    }
    __syncthreads();

    int w = t >> 6;
    int lane = t & 63;
    int l15 = lane & 15;
    int kq = lane >> 4;

    // ---- layer 1: H[32][256] = IN[32][288] @ W1, wave w owns cols [w*64, w*64+64)
    f32x4 acc[2][4] = {};
    for (int kk = 0; kk < 9; ++kk) {
        bf16x8 a[2], bw[4];
#pragma unroll
        for (int mi = 0; mi < 2; ++mi)
            a[mi] = *(const bf16x8*)&in_s[mi * 16 + l15][kk * 32 + kq * 8];
#pragma unroll
        for (int ni = 0; ni < 4; ++ni)
            bw[ni] = *(const bf16x8*)&w1t[(size_t)((w << 6) + ni * 16 + l15) * K1 + kk * 32 + kq * 8];
#pragma unroll
        for (int mi = 0; mi < 2; ++mi)
#pragma unroll
            for (int ni = 0; ni < 4; ++ni)
                acc[mi][ni] = __builtin_amdgcn_mfma_f32_16x16x32_bf16(a[mi], bw[ni], acc[mi][ni], 0, 0, 0);
    }
#pragma unroll
    for (int mi = 0; mi < 2; ++mi)
#pragma unroll
        for (int ni = 0; ni < 4; ++ni) {
            int col = (w << 6) + ni * 16 + l15;
            float bias = b1[col];
#pragma unroll
            for (int j = 0; j < 4; ++j) {
                int row = mi * 16 + kq * 4 + j;
                h_s[row][col] = f2bf(geluf(acc[mi][ni][j] + bias));
            }
        }
    __syncthreads();

    // ---- layer 2: MSG[32][128] = H[32][256] @ W2, wave w owns cols [w*32, w*32+32)
    f32x4 acc2[2][2] = {};
    for (int kk = 0; kk < 8; ++kk) {
        bf16x8 a2[2], bw2[2];
#pragma unroll
        for (int mi = 0; mi < 2; ++mi)
            a2[mi] = *(const bf16x8*)&h_s[mi * 16 + l15][kk * 32 + kq * 8];
#pragma unroll
        for (int ni = 0; ni < 2; ++ni)
            bw2[ni] = *(const bf16x8*)&w2t[(size_t)((w << 5) + ni * 16 + l15) * H1 + kk * 32 + kq * 8];
#pragma unroll
        for (int mi = 0; mi < 2; ++mi)
#pragma unroll
            for (int ni = 0; ni < 2; ++ni)
                acc2[mi][ni] = __builtin_amdgcn_mfma_f32_16x16x32_bf16(a2[mi], bw2[ni], acc2[mi][ni], 0, 0, 0);
    }
#pragma unroll
    for (int mi = 0; mi < 2; ++mi)
#pragma unroll
        for (int ni = 0; ni < 2; ++ni) {
            int col = (w << 5) + ni * 16 + l15;
            float bias = b2[col];
#pragma unroll
            for (int j = 0; j < 4; ++j) {
                int row = mi * 16 + kq * 4 + j;
                atomicAdd(&aggr[(size_t)ds[row] * DIM + col], acc2[mi][ni][j] + bias);
            }
        }
}

// --- node update MLP, MFMA ---
__global__ __launch_bounds__(256, 2) void update_mfma(const unsigned short* __restrict__ xn_bf,
                                                      const float* __restrict__ aggr,
                                                      const unsigned short* __restrict__ uw1t,
                                                      const float* __restrict__ b1,
                                                      const unsigned short* __restrict__ uw2t,
                                                      const float* __restrict__ b2,
                                                      float* __restrict__ h_local) {
    __shared__ __align__(16) unsigned short cat_s[64][UP];
    __shared__ __align__(16) unsigned short hu_s[64][HP];
    int t = threadIdx.x;
    int n0 = blockIdx.x * 64;
    for (int idx = t; idx < 64 * 32; idx += 256) {
        int e = idx >> 5, seg = idx & 31;
        if (seg < 16) {
            *(uint4*)&cat_s[e][seg * 8] = *(const uint4*)&xn_bf[(size_t)(n0 + e) * DIM + seg * 8];
        } else {
            const float* src = &aggr[(size_t)(n0 + e) * DIM + (seg - 16) * 8];
            float4 a0 = *(const float4*)src, a1 = *(const float4*)(src + 4);
            unsigned short r[8] = {f2bf(a0.x), f2bf(a0.y), f2bf(a0.z), f2bf(a0.w),
                                   f2bf(a1.x), f2bf(a1.y), f2bf(a1.z), f2bf(a1.w)};
            *(uint4*)&cat_s[e][128 + (seg - 16) * 8] = *(const uint4*)r;
        }
    }
    __syncthreads();
    int w = t >> 6, lane = t & 63, l15 = lane & 15, kq = lane >> 4;

    f32x4 acc[4][2] = {};
    for (int kk = 0; kk < 8; ++kk) {
        bf16x8 a[4], bw[2];
#pragma unroll
        for (int mi = 0; mi < 4; ++mi)
            a[mi] = *(const bf16x8*)&cat_s[mi * 16 + l15][kk * 32 + kq * 8];
#pragma unroll
        for (int ni = 0; ni < 2; ++ni)
            bw[ni] = *(const bf16x8*)&uw1t[(size_t)((w << 5) + ni * 16 + l15) * 256 + kk * 32 + kq * 8];
#pragma unroll
        for (int mi = 0; mi < 4; ++mi)
#pragma unroll
            for (int ni = 0; ni < 2; ++ni)
                acc[mi][ni] = __builtin_amdgcn_mfma_f32_16x16x32_bf16(a[mi], bw[ni], acc[mi][ni], 0, 0, 0);
    }
#pragma unroll
    for (int mi = 0; mi < 4; ++mi)
#pragma unroll
        for (int ni = 0; ni < 2; ++ni) {
            int col = (w << 5) + ni * 16 + l15;
            float bias = b1[col];
#pragma unroll
            for (int j = 0; j < 4; ++j) {
                int row = mi * 16 + kq * 4 + j;
                hu_s[row][col] = f2bf(geluf(acc[mi][ni][j] + bias));
            }
        }
    __syncthreads();

    f32x4 acc2[4][2] = {};
    for (int kk = 0; kk < 4; ++kk) {
        bf16x8 a2[4], bw2[2];
#pragma unroll
        for (int mi = 0; mi < 4; ++mi)
            a2[mi] = *(const bf16x8*)&hu_s[mi * 16 + l15][kk * 32 + kq * 8];
#pragma unroll
        for (int ni = 0; ni < 2; ++ni)
            bw2[ni] = *(const bf16x8*)&uw2t[(size_t)((w << 5) + ni * 16 + l15) * 128 + kk * 32 + kq * 8];
#pragma unroll
        for (int mi = 0; mi < 4; ++mi)
#pragma unroll
            for (int ni = 0; ni < 2; ++ni)
                acc2[mi][ni] = __builtin_amdgcn_mfma_f32_16x16x32_bf16(a2[mi], bw2[ni], acc2[mi][ni], 0, 0, 0);
    }
#pragma unroll
    for (int mi = 0; mi < 4; ++mi)
#pragma unroll
        for (int ni = 0; ni < 2; ++ni) {
            int col = (w << 5) + ni * 16 + l15;
            float bias = b2[col];
#pragma unroll
            for (int j = 0; j < 4; ++j) {
                int row = mi * 16 + kq * 4 + j;
                h_local[(size_t)(n0 + row) * DIM + col] = acc2[mi][ni][j] + bias;
            }
        }
}

// --- qkv = x @ in_w + in_b (bf16 out), MFMA ---
__global__ __launch_bounds__(256, 2) void qkv_mfma(const unsigned short* __restrict__ x_bf,
                                                   const unsigned short* __restrict__ iwt,
                                                   const float* __restrict__ b,
                                                   unsigned short* __restrict__ qkv_bf) {
    __shared__ __align__(16) unsigned short x_s[64][HP];
    int t = threadIdx.x;
    int n0 = blockIdx.x * 64;
    for (int idx = t; idx < 64 * 16; idx += 256) {
        int e = idx >> 4, seg = idx & 15;
        *(uint4*)&x_s[e][seg * 8] = *(const uint4*)&x_bf[(size_t)(n0 + e) * DIM + seg * 8];
    }
    __syncthreads();
    int w = t >> 6, lane = t & 63, l15 = lane & 15, kq = lane >> 4;

    f32x4 acc[4][6] = {};
    for (int kk = 0; kk < 4; ++kk) {
        bf16x8 a[4], bw[6];
#pragma unroll
        for (int mi = 0; mi < 4; ++mi)
            a[mi] = *(const bf16x8*)&x_s[mi * 16 + l15][kk * 32 + kq * 8];
#pragma unroll
        for (int ni = 0; ni < 6; ++ni)
            bw[ni] = *(const bf16x8*)&iwt[(size_t)(w * 96 + ni * 16 + l15) * 128 + kk * 32 + kq * 8];
#pragma unroll
        for (int mi = 0; mi < 4; ++mi)
#pragma unroll
            for (int ni = 0; ni < 6; ++ni)
                acc[mi][ni] = __builtin_amdgcn_mfma_f32_16x16x32_bf16(a[mi], bw[ni], acc[mi][ni], 0, 0, 0);
    }
#pragma unroll
    for (int mi = 0; mi < 4; ++mi)
#pragma unroll
        for (int ni = 0; ni < 6; ++ni) {
            int col = w * 96 + ni * 16 + l15;
            float bias = b[col];
#pragma unroll
            for (int j = 0; j < 4; ++j) {
                int row = mi * 16 + kq * 4 + j;
                qkv_bf[(size_t)(n0 + row) * 384 + col] = f2bf(acc[mi][ni][j] + bias);
            }
        }
}

// --- flash attention on bf16 qkv ---
__global__ __launch_bounds__(256) void attn_flash(const unsigned short* __restrict__ qkv,
                                                  float* __restrict__ o) {
    int bid = blockIdx.x;
    int quarter = bid & 3;
    int h = (bid >> 2) & 3;
    int g = bid >> 4;
    int t = threadIdx.x;
    int qi = t & 127;
    int sp = t >> 7;
    int sq = quarter * 128 + qi;
    int nq = g * SEQ + sq;

    __shared__ __align__(16) float k_s[2][CH][HD];
    __shared__ __align__(16) float v_s[2][CH][HD];
    __shared__ float merge_s[128][34];

    float qv[HD];
    const unsigned short* qr = qkv + (size_t)nq * 384 + h * HD;
#pragma unroll
    for (int d0 = 0; d0 < HD; d0 += 8) {
        uint4 raw = *(const uint4*)&qr[d0];
        const unsigned short* rs = (const unsigned short*)&raw;
#pragma unroll
        for (int j = 0; j < 8; ++j) qv[d0 + j] = bf2f(rs[j]);
    }
    const float scale = 0.17677669529663687f;
#pragma unroll
    for (int d = 0; d < HD; ++d) qv[d] *= scale;

    float m = -1e30f, l = 0.0f;
    float oacc[HD];
#pragma unroll
    for (int d = 0; d < HD; ++d) oacc[d] = 0.0f;

    int base_j = sp * 256;
    int r = qi >> 3;
    int c4 = (qi & 7) * 4;
    for (int c0 = 0; c0 < 256; c0 += CH) {
        __syncthreads();
#pragma unroll
        for (int p = 0; p < CH; p += 16) {
            int j = base_j + c0 + p + r;
            const unsigned short* kr = qkv + (size_t)(g * SEQ + j) * 384 + 128 + h * HD;
            const unsigned short* vr = qkv + (size_t)(g * SEQ + j) * 384 + 256 + h * HD;
            uint2 kraw = *(const uint2*)&kr[c4];
            uint2 vraw = *(const uint2*)&vr[c4];
            const unsigned short* kp = (const unsigned short*)&kraw;
            const unsigned short* vp = (const unsigned short*)&vraw;
            float4 kf = {bf2f(kp[0]), bf2f(kp[1]), bf2f(kp[2]), bf2f(kp[3])};
            float4 vf = {bf2f(vp[0]), bf2f(vp[1]), bf2f(vp[2]), bf2f(vp[3])};
            *(float4*)&k_s[sp][p + r][c4] = kf;
            *(float4*)&v_s[sp][p + r][c4] = vf;
        }
        __syncthreads();
        float sc[CH];
#pragma unroll
        for (int j = 0; j < CH; ++j) {
            float s = 0.0f;
#pragma unroll
            for (int d = 0; d < HD; ++d) s = fmaf(qv[d], k_s[sp][j][d], s);
            sc[j] = s;
        }
        float cm = sc[0];
#pragma unroll
        for (int j = 1; j < CH; ++j) cm = fmaxf(cm, sc[j]);
        float mn = fmaxf(m, cm);
        float corr = __expf(m - mn);
        l *= corr;
#pragma unroll
        for (int d = 0; d < HD; ++d) oacc[d] *= corr;
#pragma unroll
        for (int j = 0; j < CH; ++j) {
            float p = __expf(sc[j] - mn);
            l += p;
#pragma unroll
            for (int d = 0; d < HD; ++d) oacc[d] = fmaf(p, v_s[sp][j][d], oacc[d]);
        }
        m = mn;
    }
    __syncthreads();
    if (sp == 1) {
        merge_s[qi][0] = m;
        merge_s[qi][1] = l;
#pragma unroll
        for (int d = 0; d < HD; ++d) merge_s[qi][2 + d] = oacc[d];
    }
    __syncthreads();
    if (sp == 0) {
        float m1 = merge_s[qi][0], l1 = merge_s[qi][1];
        float mn = fmaxf(m, m1);
        float cc0 = __expf(m - mn), cc1 = __expf(m1 - mn);
        float inv = 1.0f / (cc0 * l + cc1 * l1);
        float* orow = o + (size_t)nq * DIM + h * HD;
#pragma unroll
        for (int d = 0; d < HD; ++d)
            orow[d] = (cc0 * oacc[d] + cc1 * merge_s[qi][2 + d]) * inv;
    }
}

// --- h1 = LN1(x + h_local + o @ out_w + out_b), MFMA + fused LN ---
__global__ __launch_bounds__(256, 2) void proj_res_ln_mfma(const float* __restrict__ x,
                                                           const float* __restrict__ h_local,
                                                           const float* __restrict__ o,
                                                           const unsigned short* __restrict__ owt,
                                                           const float* __restrict__ ob,
                                                           const float* __restrict__ g1,
                                                           const float* __restrict__ bb1,
                                                           float* __restrict__ h1) {
    __shared__ __align__(16) unsigned short o_s[64][HP];
    __shared__ float y_s[64][132];
    int t = threadIdx.x;
    int n0 = blockIdx.x * 64;
    for (int idx = t; idx < 64 * 16; idx += 256) {
        int e = idx >> 4, seg = idx & 15;
        const float* src = &o[(size_t)(n0 + e) * DIM + seg * 8];
        float4 a0 = *(const float4*)src, a1 = *(const float4*)(src + 4);
        unsigned short rr[8] = {f2bf(a0.x), f2bf(a0.y), f2bf(a0.z), f2bf(a0.w),
                                f2bf(a1.x), f2bf(a1.y), f2bf(a1.z), f2bf(a1.w)};
        *(uint4*)&o_s[e][seg * 8] = *(const uint4*)rr;
    }
    __syncthreads();
    int w = t >> 6, lane = t & 63, l15 = lane & 15, kq = lane >> 4;

    f32x4 acc[4][2] = {};
    for (int kk = 0; kk < 4; ++kk) {
        bf16x8 a[4], bw[2];
#pragma unroll
        for (int mi = 0; mi < 4; ++mi)
            a[mi] = *(const bf16x8*)&o_s[mi * 16 + l15][kk * 32 + kq * 8];
#pragma unroll
        for (int ni = 0; ni < 2; ++ni)
            bw[ni] = *(const bf16x8*)&owt[(size_t)((w << 5) + ni * 16 + l15) * 128 + kk * 32 + kq * 8];
#pragma unroll
        for (int mi = 0; mi < 4; ++mi)
#pragma unroll
            for (int ni = 0; ni < 2; ++ni)
                acc[mi][ni] = __builtin_amdgcn_mfma_f32_16x16x32_bf16(a[mi], bw[ni], acc[mi][ni], 0, 0, 0);
    }
#pragma unroll
    for (int mi = 0; mi < 4; ++mi)
#pragma unroll
        for (int ni = 0; ni < 2; ++ni) {
            int col = (w << 5) + ni * 16 + l15;
            float bias = ob[col];
#pragma unroll
            for (int j = 0; j < 4; ++j) {
                int row = mi * 16 + kq * 4 + j;
                size_t gi = (size_t)(n0 + row) * DIM + col;
                y_s[row][col] = x[gi] + h_local[gi] + acc[mi][ni][j] + bias;
            }
        }
    __syncthreads();
    for (int rr = 0; rr < 16; ++rr) {
        int row = (w << 4) + rr;
        float v0 = y_s[row][lane], v1 = y_s[row][lane + 64];
        float mean = waveSum(v0 + v1) * (1.0f / 128.0f);
        float d0 = v0 - mean, d1 = v1 - mean;
        float var = waveSum(d0 * d0 + d1 * d1) * (1.0f / 128.0f);
        float rs = rsqrtf(var + 1e-5f);
        float* hrow = h1 + (size_t)(n0 + row) * DIM;
        hrow[lane] = d0 * rs * g1[lane] + bb1[lane];
        hrow[lane + 64] = d1 * rs * g1[lane + 64] + bb1[lane + 64];
    }
}

// --- out = LN2(h1 + gelu(h1 @ F1 + fb1) @ F2 + fb2), MFMA + fused LN ---
__global__ __launch_bounds__(256, 1) void ffn_ln_mfma(const float* __restrict__ h1,
                                                      const unsigned short* __restrict__ fw1t,
                                                      const float* __restrict__ fb1,
                                                      const unsigned short* __restrict__ fw2t,
                                                      const float* __restrict__ fb2,
                                                      const float* __restrict__ g2,
                                                      const float* __restrict__ b2n,
                                                      float* __restrict__ out) {
    __shared__ __align__(16) unsigned short h_s[64][HP];
    __shared__ __align__(16) unsigned short hid_s[64][UP];
    __shared__ float y_s[64][132];
    int t = threadIdx.x;
    int n0 = blockIdx.x * 64;
    for (int idx = t; idx < 64 * 16; idx += 256) {
        int e = idx >> 4, seg = idx & 15;
        const float* src = &h1[(size_t)(n0 + e) * DIM + seg * 8];
        float4 a0 = *(const float4*)src, a1 = *(const float4*)(src + 4);
        unsigned short rr[8] = {f2bf(a0.x), f2bf(a0.y), f2bf(a0.z), f2bf(a0.w),
                                f2bf(a1.x), f2bf(a1.y), f2bf(a1.z), f2bf(a1.w)};
        *(uint4*)&h_s[e][seg * 8] = *(const uint4*)rr;
    }
    __syncthreads();
    int w = t >> 6, lane = t & 63, l15 = lane & 15, kq = lane >> 4;

    f32x4 acc[4][4] = {};
    for (int kk = 0; kk < 4; ++kk) {
        bf16x8 a[4], bw[4];
#pragma unroll
        for (int mi = 0; mi < 4; ++mi)
            a[mi] = *(const bf16x8*)&h_s[mi * 16 + l15][kk * 32 + kq * 8];
#pragma unroll
        for (int ni = 0; ni < 4; ++ni)
            bw[ni] = *(const bf16x8*)&fw1t[(size_t)((w << 6) + ni * 16 + l15) * 128 + kk * 32 + kq * 8];
#pragma unroll
        for (int mi = 0; mi < 4; ++mi)
#pragma unroll
            for (int ni = 0; ni < 4; ++ni)
                acc[mi][ni] = __builtin_amdgcn_mfma_f32_16x16x32_bf16(a[mi], bw[ni], acc[mi][ni], 0, 0, 0);
    }
#pragma unroll
    for (int mi = 0; mi < 4; ++mi)
#pragma unroll
        for (int ni = 0; ni < 4; ++ni) {
            int col = (w << 6) + ni * 16 + l15;
            float bias = fb1[col];
#pragma unroll
            for (int j = 0; j < 4; ++j) {
                int row = mi * 16 + kq * 4 + j;
                hid_s[row][col] = f2bf(geluf(acc[mi][ni][j] + bias));
            }
        }
    __syncthreads();

    f32x4 acc2[4][2] = {};
    for (int kk = 0; kk < 8; ++kk) {
        bf16x8 a2[4], bw2[2];
#pragma unroll
        for (int mi = 0; mi < 4; ++mi)
            a2[mi] = *(const bf16x8*)&hid_s[mi * 16 + l15][kk * 32 + kq * 8];
#pragma unroll
        for (int ni = 0; ni < 2; ++ni)
            bw2[ni] = *(const bf16x8*)&fw2t[(size_t)((w << 5) + ni * 16 + l15) * 256 + kk * 32 + kq * 8];
#pragma unroll
        for (int mi = 0; mi < 4; ++mi)
#pragma unroll
            for (int ni = 0; ni < 2; ++ni)
                acc2[mi][ni] = __builtin_amdgcn_mfma_f32_16x16x32_bf16(a2[mi], bw2[ni], acc2[mi][ni], 0, 0, 0);
    }
#pragma unroll
    for (int mi = 0; mi < 4; ++mi)
#pragma unroll
        for (int ni = 0; ni < 2; ++ni) {
            int col = (w << 5) + ni * 16 + l15;
            float bias = fb2[col];
#pragma unroll
            for (int j = 0; j < 4; ++j) {
                int row = mi * 16 + kq * 4 + j;
                y_s[row][col] = h1[(size_t)(n0 + row) * DIM + col] + acc2[mi][ni][j] + bias;
            }
        }
    __syncthreads();
    for (int rr = 0; rr < 16; ++rr) {
        int row = (w << 4) + rr;
        float v0 = y_s[row][lane], v1 = y_s[row][lane + 64];
        float mean = waveSum(v0 + v1) * (1.0f / 128.0f);
        float d0 = v0 - mean, d1 = v1 - mean;
        float var = waveSum(d0 * d0 + d1 * d1) * (1.0f / 128.0f);
        float rs = rsqrtf(var + 1e-5f);
        float* orow = out + (size_t)(n0 + row) * DIM;
        orow[lane] = d0 * rs * g2[lane] + b2n[lane];
        orow[lane + 64] = d1 * rs * g2[lane + 64] + b2n[lane + 64];
    }
}

extern "C" void kernel_launch(void* const* d_in, const int* in_sizes, int n_in,
                              void* d_out, int out_size, void* d_ws, size_t ws_size,
                              hipStream_t stream) {
    const float* x      = (const float*)d_in[0];
    const int*   ei     = (const int*)d_in[1];
    const float* attr   = (const float*)d_in[2];
    const float* gnn_g  = (const float*)d_in[4];
    const float* gnn_b  = (const float*)d_in[5];
    const float* msg_w1 = (const float*)d_in[6];
    const float* msg_b1 = (const float*)d_in[7];
    const float* msg_w2 = (const float*)d_in[8];
    const float* msg_b2 = (const float*)d_in[9];
    const float* upd_w1 = (const float*)d_in[10];
    const float* upd_b1 = (const float*)d_in[11];
    const float* upd_w2 = (const float*)d_in[12];
    const float* upd_b2 = (const float*)d_in[13];
    const float* in_w   = (const float*)d_in[14];
    const float* in_b   = (const float*)d_in[15];
    const float* out_w  = (const float*)d_in[16];
    const float* out_b  = (const float*)d_in[17];
    const float* ffn_w1 = (const float*)d_in[18];
    const float* ffn_b1 = (const float*)d_in[19];
    const float* ffn_w2 = (const float*)d_in[20];
    const float* ffn_b2 = (const float*)d_in[21];
    const float* n1_g   = (const float*)d_in[22];
    const float* n1_b   = (const float*)d_in[23];
    const float* n2_g   = (const float*)d_in[24];
    const float* n2_b   = (const float*)d_in[25];
    float* out = (float*)d_out;
    float* ws = (float*)d_ws;

    float* aggr    = ws;                                         // 2,097,152
    float* h_local = ws + 2097152;                               // 2,097,152
    unsigned short* qkv_bf = (unsigned short*)(ws + 4194304);    // 1,572,864 fl
    float* o       = ws + 5767168;                               // 2,097,152
    float* h1      = ws + 7864320;                               // 2,097,152
    unsigned short* xn_bf  = (unsigned short*)(ws + 9961472);    // 1,048,576 fl
    unsigned short* x_bf   = (unsigned short*)(ws + 11010048);   // 1,048,576 fl
    unsigned short* w1t    = (unsigned short*)(ws + 12058624);
    unsigned short* w2t    = (unsigned short*)(ws + 12095488);
    unsigned short* uw1t   = (unsigned short*)(ws + 12111872);
    unsigned short* uw2t   = (unsigned short*)(ws + 12128256);
    unsigned short* iwt    = (unsigned short*)(ws + 12136448);
    unsigned short* owt    = (unsigned short*)(ws + 12161024);
    unsigned short* fw1t   = (unsigned short*)(ws + 12169216);
    unsigned short* fw2t   = (unsigned short*)(ws + 12185600);
    unsigned short* attr_bf = (unsigned short*)(ws + 12582912);

    hipMemsetAsync(aggr, 0, (size_t)N_NODES * DIM * sizeof(float), stream);
    ln_rows_bf2<<<N_NODES / 4, 256, 0, stream>>>(x, gnn_g, gnn_b, xn_bf, x_bf);
    conv_attr<<<(NEDGE * EDIM) / (256 * 8), 256, 0, stream>>>(attr, attr_bf);
    conv_weights<<<1120, 256, 0, stream>>>(msg_w1, msg_w2, upd_w1, upd_w2, in_w, out_w, ffn_w1, ffn_w2,
                                           w1t, w2t, uw1t, uw2t, iwt, owt, fw1t, fw2t);
    edge_mlp_mfma<<<NEDGE / EB, 256, 0, stream>>>(xn_bf, ei, attr_bf, w1t, msg_b1, w2t, msg_b2, aggr);
    update_mfma<<<N_NODES / 64, 256, 0, stream>>>(xn_bf, aggr, uw1t, upd_b1, uw2t, upd_b2, h_local);
    qkv_mfma<<<N_NODES / 64, 256, 0, stream>>>(x_bf, iwt, in_b, qkv_bf);
    attn_flash<<<NG * NH * 4, 256, 0, stream>>>(qkv_bf, o);
    proj_res_ln_mfma<<<N_NODES / 64, 256, 0, stream>>>(x, h_local, o, owt, out_b, n1_g, n1_b, h1);
    ffn_ln_mfma<<<N_NODES / 64, 256, 0, stream>>>(h1, fw1t, ffn_b1, fw2t, ffn_b2, n2_g, n2_b, out);
}

// Round 12
// 418.647 us; speedup vs baseline: 8.1429x; 1.1051x over previous
//
#include <hip/hip_runtime.h>
#include <cmath>

#define N_NODES 16384
#define DIM 128
#define EDIM 32
#define NEDGE 262144
#define NG 32
#define SEQ 512
#define NH 4
#define HD 32

#define EB 32
#define K1 288
#define K1P 296
#define H1 256
#define H1P 264
#define HP 136    // 128+8 pad (ushorts)
#define UP 264    // 256+8 pad (ushorts)

typedef __bf16 bf16x8 __attribute__((ext_vector_type(8)));
typedef float f32x4 __attribute__((ext_vector_type(4)));

__device__ __forceinline__ unsigned short f2bf(float f) {
    union { float f; unsigned int u; } v; v.f = f;
    unsigned int r = (v.u + 0x7FFFu + ((v.u >> 16) & 1u)) >> 16;
    return (unsigned short)r;
}
__device__ __forceinline__ float bf2f(unsigned short u) {
    union { unsigned int u; float f; } v; v.u = ((unsigned int)u) << 16;
    return v.f;
}

// tanh-approx gelu: max |diff| vs erf-gelu ~3e-3, no branches, 1 exp
__device__ __forceinline__ float geluf(float x) {
    float z = 0.7978845608f * (x + 0.044715f * x * x * x);
    float e = __expf(2.0f * z);
    float t = 1.0f - 2.0f / (e + 1.0f);
    return 0.5f * x * (1.0f + t);
}

__device__ __forceinline__ float waveSum(float v) {
#pragma unroll
    for (int m = 1; m < 64; m <<= 1) v += __shfl_xor(v, m, 64);
    return v;
}

// --- LN over 128 features -> xn_bf (bf16); also x -> x_bf ---
__global__ __launch_bounds__(256) void ln_rows_bf2(const float* __restrict__ x,
                                                   const float* __restrict__ g,
                                                   const float* __restrict__ b,
                                                   unsigned short* __restrict__ xn_bf,
                                                   unsigned short* __restrict__ x_bf) {
    int wave = threadIdx.x >> 6;
    int lane = threadIdx.x & 63;
    int row = blockIdx.x * 4 + wave;
    const float* xr = x + (size_t)row * DIM;
    float v0 = xr[lane], v1 = xr[lane + 64];
    unsigned short* xbf = x_bf + (size_t)row * DIM;
    xbf[lane] = f2bf(v0);
    xbf[lane + 64] = f2bf(v1);
    float mean = waveSum(v0 + v1) * (1.0f / 128.0f);
    float d0 = v0 - mean, d1 = v1 - mean;
    float var = waveSum(d0 * d0 + d1 * d1) * (1.0f / 128.0f);
    float r = rsqrtf(var + 1e-5f);
    unsigned short* obf = xn_bf + (size_t)row * DIM;
    obf[lane] = f2bf(d0 * r * g[lane] + b[lane]);
    obf[lane + 64] = f2bf(d1 * r * g[lane + 64] + b[lane + 64]);
}

// --- attr f32 -> bf16 ---
__global__ __launch_bounds__(256) void conv_attr(const float* __restrict__ a,
                                                 unsigned short* __restrict__ abf) {
    size_t i = ((size_t)blockIdx.x * 256 + threadIdx.x) * 8;
    float4 x0 = *(const float4*)&a[i];
    float4 x1 = *(const float4*)&a[i + 4];
    unsigned short r[8];
    r[0] = f2bf(x0.x); r[1] = f2bf(x0.y); r[2] = f2bf(x0.z); r[3] = f2bf(x0.w);
    r[4] = f2bf(x1.x); r[5] = f2bf(x1.y); r[6] = f2bf(x1.z); r[7] = f2bf(x1.w);
    *(uint4*)&abf[i] = *(const uint4*)r;
}

// --- all 8 weight transposes+conversions fused ---
__global__ __launch_bounds__(256) void conv_weights(
    const float* __restrict__ s0, const float* __restrict__ s1,
    const float* __restrict__ s2, const float* __restrict__ s3,
    const float* __restrict__ s4, const float* __restrict__ s5,
    const float* __restrict__ s6, const float* __restrict__ s7,
    unsigned short* __restrict__ d0, unsigned short* __restrict__ d1,
    unsigned short* __restrict__ d2, unsigned short* __restrict__ d3,
    unsigned short* __restrict__ d4, unsigned short* __restrict__ d5,
    unsigned short* __restrict__ d6, unsigned short* __restrict__ d7) {
    int i = blockIdx.x * 256 + threadIdx.x;
    if (i < 73728)        { int k = i >> 8, n = i & 255;                 d0[n * 288 + k] = f2bf(s0[i]); }
    else if (i < 106496)  { int j = i - 73728;  int k = j >> 7, n = j & 127; d1[n * 256 + k] = f2bf(s1[j]); }
    else if (i < 139264)  { int j = i - 106496; int k = j >> 7, n = j & 127; d2[n * 256 + k] = f2bf(s2[j]); }
    else if (i < 155648)  { int j = i - 139264; int k = j >> 7, n = j & 127; d3[n * 128 + k] = f2bf(s3[j]); }
    else if (i < 204800)  { int j = i - 155648; int k = j / 384, n = j - k * 384; d4[n * 128 + k] = f2bf(s4[j]); }
    else if (i < 221184)  { int j = i - 204800; int k = j >> 7, n = j & 127; d5[n * 128 + k] = f2bf(s5[j]); }
    else if (i < 253952)  { int j = i - 221184; int k = j >> 8, n = j & 255; d6[n * 128 + k] = f2bf(s6[j]); }
    else if (i < 286720)  { int j = i - 253952; int k = j >> 7, n = j & 127; d7[n * 256 + k] = f2bf(s7[j]); }
}

// --- edge MLP, bf16 MFMA: 32 edges/block, 4 waves, 4 blocks/CU ---
__global__ __launch_bounds__(256, 4) void edge_mlp_mfma(const unsigned short* __restrict__ xn_bf,
                                                        const int* __restrict__ ei,
                                                        const unsigned short* __restrict__ attr_bf,
                                                        const unsigned short* __restrict__ w1t,
                                                        const float* __restrict__ b1,
                                                        const unsigned short* __restrict__ w2t,
                                                        const float* __restrict__ b2,
                                                        float* __restrict__ aggr) {
    __shared__ __align__(16) unsigned short in_s[EB][K1P];  // 18944 B
    __shared__ __align__(16) unsigned short h_s[EB][H1P];   // 16896 B
    __shared__ int ds[EB], ss[EB];
    int t = threadIdx.x;
    int eb0 = blockIdx.x * EB;
    if (t < EB) ds[t] = ei[NEDGE + eb0 + t];
    else if (t < 2 * EB) ss[t - EB] = ei[eb0 + t - EB];
    __syncthreads();
    // stage IN = [xn[dst] | xn[src] | attr], 36 x 16B per edge
    for (int idx = t; idx < EB * 36; idx += 256) {
        int e = idx / 36;
        int seg = idx - e * 36;
        const unsigned short* src;
        if (seg < 16)      src = xn_bf + (size_t)ds[e] * DIM + seg * 8;
        else if (seg < 32) src = xn_bf + (size_t)ss[e] * DIM + (seg - 16) * 8;
        else               src = attr_bf + (size_t)(eb0 + e) * EDIM + (seg - 32) * 8;
        *(uint4*)&in_s[e][seg * 8] = *(const uint4*)src;
    }
    __syncthreads();

    int w = t >> 6;
    int lane = t & 63;
    int l15 = lane & 15;
    int kq = lane >> 4;

    // ---- layer 1: H[32][256] = IN[32][288] @ W1, wave w owns cols [w*64, w*64+64)
    f32x4 acc[2][4] = {};
    for (int kk = 0; kk < 9; ++kk) {
        bf16x8 a[2], bw[4];
#pragma unroll
        for (int mi = 0; mi < 2; ++mi)
            a[mi] = *(const bf16x8*)&in_s[mi * 16 + l15][kk * 32 + kq * 8];
#pragma unroll
        for (int ni = 0; ni < 4; ++ni)
            bw[ni] = *(const bf16x8*)&w1t[(size_t)((w << 6) + ni * 16 + l15) * K1 + kk * 32 + kq * 8];
#pragma unroll
        for (int mi = 0; mi < 2; ++mi)
#pragma unroll
            for (int ni = 0; ni < 4; ++ni)
                acc[mi][ni] = __builtin_amdgcn_mfma_f32_16x16x32_bf16(a[mi], bw[ni], acc[mi][ni], 0, 0, 0);
    }
#pragma unroll
    for (int mi = 0; mi < 2; ++mi)
#pragma unroll
        for (int ni = 0; ni < 4; ++ni) {
            int col = (w << 6) + ni * 16 + l15;
            float bias = b1[col];
#pragma unroll
            for (int j = 0; j < 4; ++j) {
                int row = mi * 16 + kq * 4 + j;
                h_s[row][col] = f2bf(geluf(acc[mi][ni][j] + bias));
            }
        }
    __syncthreads();

    // ---- layer 2: MSG[32][128] = H[32][256] @ W2, wave w owns cols [w*32, w*32+32)
    f32x4 acc2[2][2] = {};
    for (int kk = 0; kk < 8; ++kk) {
        bf16x8 a2[2], bw2[2];
#pragma unroll
        for (int mi = 0; mi < 2; ++mi)
            a2[mi] = *(const bf16x8*)&h_s[mi * 16 + l15][kk * 32 + kq * 8];
#pragma unroll
        for (int ni = 0; ni < 2; ++ni)
            bw2[ni] = *(const bf16x8*)&w2t[(size_t)((w << 5) + ni * 16 + l15) * H1 + kk * 32 + kq * 8];
#pragma unroll
        for (int mi = 0; mi < 2; ++mi)
#pragma unroll
            for (int ni = 0; ni < 2; ++ni)
                acc2[mi][ni] = __builtin_amdgcn_mfma_f32_16x16x32_bf16(a2[mi], bw2[ni], acc2[mi][ni], 0, 0, 0);
    }
#pragma unroll
    for (int mi = 0; mi < 2; ++mi)
#pragma unroll
        for (int ni = 0; ni < 2; ++ni) {
            int col = (w << 5) + ni * 16 + l15;
            float bias = b2[col];
#pragma unroll
            for (int j = 0; j < 4; ++j) {
                int row = mi * 16 + kq * 4 + j;
                atomicAdd(&aggr[(size_t)ds[row] * DIM + col], acc2[mi][ni][j] + bias);
            }
        }
}

// --- node update MLP, MFMA ---
__global__ __launch_bounds__(256, 2) void update_mfma(const unsigned short* __restrict__ xn_bf,
                                                      const float* __restrict__ aggr,
                                                      const unsigned short* __restrict__ uw1t,
                                                      const float* __restrict__ b1,
                                                      const unsigned short* __restrict__ uw2t,
                                                      const float* __restrict__ b2,
                                                      float* __restrict__ h_local) {
    __shared__ __align__(16) unsigned short cat_s[64][UP];
    __shared__ __align__(16) unsigned short hu_s[64][HP];
    int t = threadIdx.x;
    int n0 = blockIdx.x * 64;
    for (int idx = t; idx < 64 * 32; idx += 256) {
        int e = idx >> 5, seg = idx & 31;
        if (seg < 16) {
            *(uint4*)&cat_s[e][seg * 8] = *(const uint4*)&xn_bf[(size_t)(n0 + e) * DIM + seg * 8];
        } else {
            const float* src = &aggr[(size_t)(n0 + e) * DIM + (seg - 16) * 8];
            float4 a0 = *(const float4*)src, a1 = *(const float4*)(src + 4);
            unsigned short r[8] = {f2bf(a0.x), f2bf(a0.y), f2bf(a0.z), f2bf(a0.w),
                                   f2bf(a1.x), f2bf(a1.y), f2bf(a1.z), f2bf(a1.w)};
            *(uint4*)&cat_s[e][128 + (seg - 16) * 8] = *(const uint4*)r;
        }
    }
    __syncthreads();
    int w = t >> 6, lane = t & 63, l15 = lane & 15, kq = lane >> 4;

    f32x4 acc[4][2] = {};
    for (int kk = 0; kk < 8; ++kk) {
        bf16x8 a[4], bw[2];
#pragma unroll
        for (int mi = 0; mi < 4; ++mi)
            a[mi] = *(const bf16x8*)&cat_s[mi * 16 + l15][kk * 32 + kq * 8];
#pragma unroll
        for (int ni = 0; ni < 2; ++ni)
            bw[ni] = *(const bf16x8*)&uw1t[(size_t)((w << 5) + ni * 16 + l15) * 256 + kk * 32 + kq * 8];
#pragma unroll
        for (int mi = 0; mi < 4; ++mi)
#pragma unroll
            for (int ni = 0; ni < 2; ++ni)
                acc[mi][ni] = __builtin_amdgcn_mfma_f32_16x16x32_bf16(a[mi], bw[ni], acc[mi][ni], 0, 0, 0);
    }
#pragma unroll
    for (int mi = 0; mi < 4; ++mi)
#pragma unroll
        for (int ni = 0; ni < 2; ++ni) {
            int col = (w << 5) + ni * 16 + l15;
            float bias = b1[col];
#pragma unroll
            for (int j = 0; j < 4; ++j) {
                int row = mi * 16 + kq * 4 + j;
                hu_s[row][col] = f2bf(geluf(acc[mi][ni][j] + bias));
            }
        }
    __syncthreads();

    f32x4 acc2[4][2] = {};
    for (int kk = 0; kk < 4; ++kk) {
        bf16x8 a2[4], bw2[2];
#pragma unroll
        for (int mi = 0; mi < 4; ++mi)
            a2[mi] = *(const bf16x8*)&hu_s[mi * 16 + l15][kk * 32 + kq * 8];
#pragma unroll
        for (int ni = 0; ni < 2; ++ni)
            bw2[ni] = *(const bf16x8*)&uw2t[(size_t)((w << 5) + ni * 16 + l15) * 128 + kk * 32 + kq * 8];
#pragma unroll
        for (int mi = 0; mi < 4; ++mi)
#pragma unroll
            for (int ni = 0; ni < 2; ++ni)
                acc2[mi][ni] = __builtin_amdgcn_mfma_f32_16x16x32_bf16(a2[mi], bw2[ni], acc2[mi][ni], 0, 0, 0);
    }
#pragma unroll
    for (int mi = 0; mi < 4; ++mi)
#pragma unroll
        for (int ni = 0; ni < 2; ++ni) {
            int col = (w << 5) + ni * 16 + l15;
            float bias = b2[col];
#pragma unroll
            for (int j = 0; j < 4; ++j) {
                int row = mi * 16 + kq * 4 + j;
                h_local[(size_t)(n0 + row) * DIM + col] = acc2[mi][ni][j] + bias;
            }
        }
}

// --- qkv = x @ in_w + in_b (bf16 out), MFMA ---
__global__ __launch_bounds__(256, 2) void qkv_mfma(const unsigned short* __restrict__ x_bf,
                                                   const unsigned short* __restrict__ iwt,
                                                   const float* __restrict__ b,
                                                   unsigned short* __restrict__ qkv_bf) {
    __shared__ __align__(16) unsigned short x_s[64][HP];
    int t = threadIdx.x;
    int n0 = blockIdx.x * 64;
    for (int idx = t; idx < 64 * 16; idx += 256) {
        int e = idx >> 4, seg = idx & 15;
        *(uint4*)&x_s[e][seg * 8] = *(const uint4*)&x_bf[(size_t)(n0 + e) * DIM + seg * 8];
    }
    __syncthreads();
    int w = t >> 6, lane = t & 63, l15 = lane & 15, kq = lane >> 4;

    f32x4 acc[4][6] = {};
    for (int kk = 0; kk < 4; ++kk) {
        bf16x8 a[4], bw[6];
#pragma unroll
        for (int mi = 0; mi < 4; ++mi)
            a[mi] = *(const bf16x8*)&x_s[mi * 16 + l15][kk * 32 + kq * 8];
#pragma unroll
        for (int ni = 0; ni < 6; ++ni)
            bw[ni] = *(const bf16x8*)&iwt[(size_t)(w * 96 + ni * 16 + l15) * 128 + kk * 32 + kq * 8];
#pragma unroll
        for (int mi = 0; mi < 4; ++mi)
#pragma unroll
            for (int ni = 0; ni < 6; ++ni)
                acc[mi][ni] = __builtin_amdgcn_mfma_f32_16x16x32_bf16(a[mi], bw[ni], acc[mi][ni], 0, 0, 0);
    }
#pragma unroll
    for (int mi = 0; mi < 4; ++mi)
#pragma unroll
        for (int ni = 0; ni < 6; ++ni) {
            int col = w * 96 + ni * 16 + l15;
            float bias = b[col];
#pragma unroll
            for (int j = 0; j < 4; ++j) {
                int row = mi * 16 + kq * 4 + j;
                qkv_bf[(size_t)(n0 + row) * 384 + col] = f2bf(acc[mi][ni][j] + bias);
            }
        }
}

// --- MFMA flash attention: block = (g, h, q-block of 128); 4 waves x 32 q-rows ---
// Fragment conventions identical to edge kernel (verified):
//   A: lane reads [row = mi*16 + l15][k = kq*8 .. +8]
//   B: lane reads [n  = ni*16 + l15][k = kq*8 .. +8]
//   C: col = l15 (+16*ni), row = kq*4 + j (+16*mi)
__global__ __launch_bounds__(256, 2) void attn_mfma(const unsigned short* __restrict__ qkv,
                                                    float* __restrict__ o) {
    int bid = blockIdx.x;
    int qb = bid & 3;
    int h = (bid >> 2) & 3;
    int g = bid >> 4;
    int t = threadIdx.x;
    int w = t >> 6, lane = t & 63, l15 = lane & 15, kq = lane >> 4;

    __shared__ __align__(16) unsigned short k_s[SEQ][34];    // [key][d]   34,816 B
    __shared__ __align__(16) unsigned short vT_s[HD][516];   // [d][key]   33,024 B
    __shared__ __align__(16) unsigned short p_s[4][32][36];  // per-wave P  9,216 B

    // stage K rows (vectorized)
    for (int idx = t; idx < SEQ * 4; idx += 256) {
        int key = idx >> 2, seg = idx & 3;
        *(uint4*)&k_s[key][seg * 8] =
            *(const uint4*)&qkv[(size_t)(g * SEQ + key) * 384 + 128 + h * HD + seg * 8];
    }
    // stage V transposed: read vectorized, write scalar
    for (int idx = t; idx < SEQ * 4; idx += 256) {
        int key = idx >> 2, seg = idx & 3;
        uint4 raw = *(const uint4*)&qkv[(size_t)(g * SEQ + key) * 384 + 256 + h * HD + seg * 8];
        const unsigned short* rp = (const unsigned short*)&raw;
#pragma unroll
        for (int j = 0; j < 8; ++j) vT_s[seg * 8 + j][key] = rp[j];
    }
    // Q straight into A-fragments from global
    int qrow0 = g * SEQ + qb * 128 + w * 32;
    bf16x8 qA[2];
#pragma unroll
    for (int mi = 0; mi < 2; ++mi)
        qA[mi] = *(const bf16x8*)&qkv[(size_t)(qrow0 + mi * 16 + l15) * 384 + h * HD + kq * 8];
    __syncthreads();  // only barrier: K/V read-only afterwards, p_s is wave-private

    const float scale = 0.17677669529663687f;  // 1/sqrt(32)
    float m[2][4], l[2][4];
    f32x4 oa[2][2] = {};
#pragma unroll
    for (int mi = 0; mi < 2; ++mi)
#pragma unroll
        for (int j = 0; j < 4; ++j) { m[mi][j] = -1e30f; l[mi][j] = 0.0f; }

    for (int kt = 0; kt < 16; ++kt) {
        // QK^T tile: S[32 q][32 keys]
        bf16x8 kB[2];
#pragma unroll
        for (int ni = 0; ni < 2; ++ni)
            kB[ni] = *(const bf16x8*)&k_s[kt * 32 + ni * 16 + l15][kq * 8];
        f32x4 s[2][2] = {};
#pragma unroll
        for (int mi = 0; mi < 2; ++mi)
#pragma unroll
            for (int ni = 0; ni < 2; ++ni)
                s[mi][ni] = __builtin_amdgcn_mfma_f32_16x16x32_bf16(qA[mi], kB[ni], s[mi][ni], 0, 0, 0);
        // online softmax: each 16-lane group (fixed kq) holds one row's 16 keys per ni
#pragma unroll
        for (int mi = 0; mi < 2; ++mi) {
#pragma unroll
            for (int j = 0; j < 4; ++j) {
                float s0 = s[mi][0][j] * scale;
                float s1 = s[mi][1][j] * scale;
                float cm = fmaxf(s0, s1);
#pragma unroll
                for (int msk = 1; msk < 16; msk <<= 1) cm = fmaxf(cm, __shfl_xor(cm, msk, 64));
                float mn = fmaxf(m[mi][j], cm);
                float corr = __expf(m[mi][j] - mn);
                float p0 = __expf(s0 - mn);
                float p1 = __expf(s1 - mn);
                float rs = p0 + p1;
#pragma unroll
                for (int msk = 1; msk < 16; msk <<= 1) rs += __shfl_xor(rs, msk, 64);
                l[mi][j] = l[mi][j] * corr + rs;
                m[mi][j] = mn;
#pragma unroll
                for (int nd = 0; nd < 2; ++nd) oa[mi][nd][j] *= corr;
                int prow = mi * 16 + kq * 4 + j;
                p_s[w][prow][l15] = f2bf(p0);
                p_s[w][prow][l15 + 16] = f2bf(p1);
            }
        }
        // PV tile: O += P @ V  (P via per-wave LDS round-trip into A-frag form)
        bf16x8 pA[2], vB[2];
#pragma unroll
        for (int mi = 0; mi < 2; ++mi)
            pA[mi] = *(const bf16x8*)&p_s[w][mi * 16 + l15][kq * 8];
#pragma unroll
        for (int nd = 0; nd < 2; ++nd)
            vB[nd] = *(const bf16x8*)&vT_s[nd * 16 + l15][kt * 32 + kq * 8];
#pragma unroll
        for (int mi = 0; mi < 2; ++mi)
#pragma unroll
            for (int nd = 0; nd < 2; ++nd)
                oa[mi][nd] = __builtin_amdgcn_mfma_f32_16x16x32_bf16(pA[mi], vB[nd], oa[mi][nd], 0, 0, 0);
    }
    // epilogue: normalize and store
#pragma unroll
    for (int mi = 0; mi < 2; ++mi)
#pragma unroll
        for (int j = 0; j < 4; ++j) {
            float inv = 1.0f / l[mi][j];
            int row = qrow0 + mi * 16 + kq * 4 + j;
            float* orow = o + (size_t)row * DIM + h * HD;
#pragma unroll
            for (int nd = 0; nd < 2; ++nd)
                orow[nd * 16 + l15] = oa[mi][nd][j] * inv;
        }
}

// --- h1 = LN1(x + h_local + o @ out_w + out_b), MFMA + fused LN ---
__global__ __launch_bounds__(256, 2) void proj_res_ln_mfma(const float* __restrict__ x,
                                                           const float* __restrict__ h_local,
                                                           const float* __restrict__ o,
                                                           const unsigned short* __restrict__ owt,
                                                           const float* __restrict__ ob,
                                                           const float* __restrict__ g1,
                                                           const float* __restrict__ bb1,
                                                           float* __restrict__ h1) {
    __shared__ __align__(16) unsigned short o_s[64][HP];
    __shared__ float y_s[64][132];
    int t = threadIdx.x;
    int n0 = blockIdx.x * 64;
    for (int idx = t; idx < 64 * 16; idx += 256) {
        int e = idx >> 4, seg = idx & 15;
        const float* src = &o[(size_t)(n0 + e) * DIM + seg * 8];
        float4 a0 = *(const float4*)src, a1 = *(const float4*)(src + 4);
        unsigned short rr[8] = {f2bf(a0.x), f2bf(a0.y), f2bf(a0.z), f2bf(a0.w),
                                f2bf(a1.x), f2bf(a1.y), f2bf(a1.z), f2bf(a1.w)};
        *(uint4*)&o_s[e][seg * 8] = *(const uint4*)rr;
    }
    __syncthreads();
    int w = t >> 6, lane = t & 63, l15 = lane & 15, kq = lane >> 4;

    f32x4 acc[4][2] = {};
    for (int kk = 0; kk < 4; ++kk) {
        bf16x8 a[4], bw[2];
#pragma unroll
        for (int mi = 0; mi < 4; ++mi)
            a[mi] = *(const bf16x8*)&o_s[mi * 16 + l15][kk * 32 + kq * 8];
#pragma unroll
        for (int ni = 0; ni < 2; ++ni)
            bw[ni] = *(const bf16x8*)&owt[(size_t)((w << 5) + ni * 16 + l15) * 128 + kk * 32 + kq * 8];
#pragma unroll
        for (int mi = 0; mi < 4; ++mi)
#pragma unroll
            for (int ni = 0; ni < 2; ++ni)
                acc[mi][ni] = __builtin_amdgcn_mfma_f32_16x16x32_bf16(a[mi], bw[ni], acc[mi][ni], 0, 0, 0);
    }
#pragma unroll
    for (int mi = 0; mi < 4; ++mi)
#pragma unroll
        for (int ni = 0; ni < 2; ++ni) {
            int col = (w << 5) + ni * 16 + l15;
            float bias = ob[col];
#pragma unroll
            for (int j = 0; j < 4; ++j) {
                int row = mi * 16 + kq * 4 + j;
                size_t gi = (size_t)(n0 + row) * DIM + col;
                y_s[row][col] = x[gi] + h_local[gi] + acc[mi][ni][j] + bias;
            }
        }
    __syncthreads();
    for (int rr = 0; rr < 16; ++rr) {
        int row = (w << 4) + rr;
        float v0 = y_s[row][lane], v1 = y_s[row][lane + 64];
        float mean = waveSum(v0 + v1) * (1.0f / 128.0f);
        float d0 = v0 - mean, d1 = v1 - mean;
        float var = waveSum(d0 * d0 + d1 * d1) * (1.0f / 128.0f);
        float rs = rsqrtf(var + 1e-5f);
        float* hrow = h1 + (size_t)(n0 + row) * DIM;
        hrow[lane] = d0 * rs * g1[lane] + bb1[lane];
        hrow[lane + 64] = d1 * rs * g1[lane + 64] + bb1[lane + 64];
    }
}

// --- out = LN2(h1 + gelu(h1 @ F1 + fb1) @ F2 + fb2), MFMA + fused LN ---
__global__ __launch_bounds__(256, 1) void ffn_ln_mfma(const float* __restrict__ h1,
                                                      const unsigned short* __restrict__ fw1t,
                                                      const float* __restrict__ fb1,
                                                      const unsigned short* __restrict__ fw2t,
                                                      const float* __restrict__ fb2,
                                                      const float* __restrict__ g2,
                                                      const float* __restrict__ b2n,
                                                      float* __restrict__ out) {
    __shared__ __align__(16) unsigned short h_s[64][HP];
    __shared__ __align__(16) unsigned short hid_s[64][UP];
    __shared__ float y_s[64][132];
    int t = threadIdx.x;
    int n0 = blockIdx.x * 64;
    for (int idx = t; idx < 64 * 16; idx += 256) {
        int e = idx >> 4, seg = idx & 15;
        const float* src = &h1[(size_t)(n0 + e) * DIM + seg * 8];
        float4 a0 = *(const float4*)src, a1 = *(const float4*)(src + 4);
        unsigned short rr[8] = {f2bf(a0.x), f2bf(a0.y), f2bf(a0.z), f2bf(a0.w),
                                f2bf(a1.x), f2bf(a1.y), f2bf(a1.z), f2bf(a1.w)};
        *(uint4*)&h_s[e][seg * 8] = *(const uint4*)rr;
    }
    __syncthreads();
    int w = t >> 6, lane = t & 63, l15 = lane & 15, kq = lane >> 4;

    f32x4 acc[4][4] = {};
    for (int kk = 0; kk < 4; ++kk) {
        bf16x8 a[4], bw[4];
#pragma unroll
        for (int mi = 0; mi < 4; ++mi)
            a[mi] = *(const bf16x8*)&h_s[mi * 16 + l15][kk * 32 + kq * 8];
#pragma unroll
        for (int ni = 0; ni < 4; ++ni)
            bw[ni] = *(const bf16x8*)&fw1t[(size_t)((w << 6) + ni * 16 + l15) * 128 + kk * 32 + kq * 8];
#pragma unroll
        for (int mi = 0; mi < 4; ++mi)
#pragma unroll
            for (int ni = 0; ni < 4; ++ni)
                acc[mi][ni] = __builtin_amdgcn_mfma_f32_16x16x32_bf16(a[mi], bw[ni], acc[mi][ni], 0, 0, 0);
    }
#pragma unroll
    for (int mi = 0; mi < 4; ++mi)
#pragma unroll
        for (int ni = 0; ni < 4; ++ni) {
            int col = (w << 6) + ni * 16 + l15;
            float bias = fb1[col];
#pragma unroll
            for (int j = 0; j < 4; ++j) {
                int row = mi * 16 + kq * 4 + j;
                hid_s[row][col] = f2bf(geluf(acc[mi][ni][j] + bias));
            }
        }
    __syncthreads();

    f32x4 acc2[4][2] = {};
    for (int kk = 0; kk < 8; ++kk) {
        bf16x8 a2[4], bw2[2];
#pragma unroll
        for (int mi = 0; mi < 4; ++mi)
            a2[mi] = *(const bf16x8*)&hid_s[mi * 16 + l15][kk * 32 + kq * 8];
#pragma unroll
        for (int ni = 0; ni < 2; ++ni)
            bw2[ni] = *(const bf16x8*)&fw2t[(size_t)((w << 5) + ni * 16 + l15) * 256 + kk * 32 + kq * 8];
#pragma unroll
        for (int mi = 0; mi < 4; ++mi)
#pragma unroll
            for (int ni = 0; ni < 2; ++ni)
                acc2[mi][ni] = __builtin_amdgcn_mfma_f32_16x16x32_bf16(a2[mi], bw2[ni], acc2[mi][ni], 0, 0, 0);
    }
#pragma unroll
    for (int mi = 0; mi < 4; ++mi)
#pragma unroll
        for (int ni = 0; ni < 2; ++ni) {
            int col = (w << 5) + ni * 16 + l15;
            float bias = fb2[col];
#pragma unroll
            for (int j = 0; j < 4; ++j) {
                int row = mi * 16 + kq * 4 + j;
                y_s[row][col] = h1[(size_t)(n0 + row) * DIM + col] + acc2[mi][ni][j] + bias;
            }
        }
    __syncthreads();
    for (int rr = 0; rr < 16; ++rr) {
        int row = (w << 4) + rr;
        float v0 = y_s[row][lane], v1 = y_s[row][lane + 64];
        float mean = waveSum(v0 + v1) * (1.0f / 128.0f);
        float d0 = v0 - mean, d1 = v1 - mean;
        float var = waveSum(d0 * d0 + d1 * d1) * (1.0f / 128.0f);
        float rs = rsqrtf(var + 1e-5f);
        float* orow = out + (size_t)(n0 + row) * DIM;
        orow[lane] = d0 * rs * g2[lane] + b2n[lane];
        orow[lane + 64] = d1 * rs * g2[lane + 64] + b2n[lane + 64];
    }
}

extern "C" void kernel_launch(void* const* d_in, const int* in_sizes, int n_in,
                              void* d_out, int out_size, void* d_ws, size_t ws_size,
                              hipStream_t stream) {
    const float* x      = (const float*)d_in[0];
    const int*   ei     = (const int*)d_in[1];
    const float* attr   = (const float*)d_in[2];
    const float* gnn_g  = (const float*)d_in[4];
    const float* gnn_b  = (const float*)d_in[5];
    const float* msg_w1 = (const float*)d_in[6];
    const float* msg_b1 = (const float*)d_in[7];
    const float* msg_w2 = (const float*)d_in[8];
    const float* msg_b2 = (const float*)d_in[9];
    const float* upd_w1 = (const float*)d_in[10];
    const float* upd_b1 = (const float*)d_in[11];
    const float* upd_w2 = (const float*)d_in[12];
    const float* upd_b2 = (const float*)d_in[13];
    const float* in_w   = (const float*)d_in[14];
    const float* in_b   = (const float*)d_in[15];
    const float* out_w  = (const float*)d_in[16];
    const float* out_b  = (const float*)d_in[17];
    const float* ffn_w1 = (const float*)d_in[18];
    const float* ffn_b1 = (const float*)d_in[19];
    const float* ffn_w2 = (const float*)d_in[20];
    const float* ffn_b2 = (const float*)d_in[21];
    const float* n1_g   = (const float*)d_in[22];
    const float* n1_b   = (const float*)d_in[23];
    const float* n2_g   = (const float*)d_in[24];
    const float* n2_b   = (const float*)d_in[25];
    float* out = (float*)d_out;
    float* ws = (float*)d_ws;

    float* aggr    = ws;                                         // 2,097,152
    float* h_local = ws + 2097152;                               // 2,097,152
    unsigned short* qkv_bf = (unsigned short*)(ws + 4194304);    // 1,572,864 fl
    float* o       = ws + 5767168;                               // 2,097,152
    float* h1      = ws + 7864320;                               // 2,097,152
    unsigned short* xn_bf  = (unsigned short*)(ws + 9961472);    // 1,048,576 fl
    unsigned short* x_bf   = (unsigned short*)(ws + 11010048);   // 1,048,576 fl
    unsigned short* w1t    = (unsigned short*)(ws + 12058624);
    unsigned short* w2t    = (unsigned short*)(ws + 12095488);
    unsigned short* uw1t   = (unsigned short*)(ws + 12111872);
    unsigned short* uw2t   = (unsigned short*)(ws + 12128256);
    unsigned short* iwt    = (unsigned short*)(ws + 12136448);
    unsigned short* owt    = (unsigned short*)(ws + 12161024);
    unsigned short* fw1t   = (unsigned short*)(ws + 12169216);
    unsigned short* fw2t   = (unsigned short*)(ws + 12185600);
    unsigned short* attr_bf = (unsigned short*)(ws + 12582912);

    hipMemsetAsync(aggr, 0, (size_t)N_NODES * DIM * sizeof(float), stream);
    ln_rows_bf2<<<N_NODES / 4, 256, 0, stream>>>(x, gnn_g, gnn_b, xn_bf, x_bf);
    conv_attr<<<(NEDGE * EDIM) / (256 * 8), 256, 0, stream>>>(attr, attr_bf);
    conv_weights<<<1120, 256, 0, stream>>>(msg_w1, msg_w2, upd_w1, upd_w2, in_w, out_w, ffn_w1, ffn_w2,
                                           w1t, w2t, uw1t, uw2t, iwt, owt, fw1t, fw2t);
    edge_mlp_mfma<<<NEDGE / EB, 256, 0, stream>>>(xn_bf, ei, attr_bf, w1t, msg_b1, w2t, msg_b2, aggr);
    update_mfma<<<N_NODES / 64, 256, 0, stream>>>(xn_bf, aggr, uw1t, upd_b1, uw2t, upd_b2, h_local);
    qkv_mfma<<<N_NODES / 64, 256, 0, stream>>>(x_bf, iwt, in_b, qkv_bf);
    attn_mfma<<<NG * NH * 4, 256, 0, stream>>>(qkv_bf, o);
    proj_res_ln_mfma<<<N_NODES / 64, 256, 0, stream>>>(x, h_local, o, owt, out_b, n1_g, n1_b, h1);
    ffn_ln_mfma<<<N_NODES / 64, 256, 0, stream>>>(h1, fw1t, ffn_b1, fw2t, ffn_b2, n2_g, n2_b, out);
}